// Round 1
// baseline (7858.038 us; speedup 1.0000x reference)
//
#include <hip/hip_runtime.h>

#define E_N 100000
#define NTOT 84000

// node types: 0=ts 1=vital 2=diag 3=med 4=proc
__device__ __forceinline__ int ntype_of(int n) {
    if (n < 50000) return 0;
    if (n < 51000) return 1;
    if (n < 71000) return 2;
    if (n < 76000) return 3;
    return 4;
}

// order-preserving float<->uint encode for atomic max
__device__ __forceinline__ unsigned enc_f(float f) {
    unsigned u = __float_as_uint(f);
    return (u & 0x80000000u) ? ~u : (u | 0x80000000u);
}
__device__ __forceinline__ float dec_f(unsigned u) {
    return (u & 0x80000000u) ? __uint_as_float(u & 0x7FFFFFFFu) : __uint_as_float(~u);
}

__device__ __forceinline__ void atomAddF(float* p, float v) {
    unsafeAtomicAdd(p, v);   // native global_atomic_add_f32 on gfx950
}

__device__ __forceinline__ float lrelu(float v) { return v >= 0.f ? v : 0.2f * v; }

// ---------------- fp32 GEMM: C[M x 256] = A[M x K] @ B[K x 256] (+bias) ----------------
// tile 64x64x16, 256 threads, 4x4 micro-tile
__global__ __launch_bounds__(256) void gemm_f32(const float* __restrict__ A,
                                                const float* __restrict__ B,
                                                float* __restrict__ C,
                                                const float* __restrict__ bias,
                                                int M, int K)
{
    __shared__ __align__(16) float As[16][68];
    __shared__ __align__(16) float Bs[16][68];
    const int tid = threadIdx.x;
    const int bm = blockIdx.x * 64;
    const int bn = blockIdx.y * 64;
    const int ty = tid >> 4, tx = tid & 15;
    const int mA = tid >> 2, kA = (tid & 3) << 2;
    const int kB = tid >> 4, nB = (tid & 15) << 2;
    float acc[4][4] = {};
    for (int k0 = 0; k0 < K; k0 += 16) {
        float4 av = make_float4(0.f, 0.f, 0.f, 0.f);
        int arow = bm + mA;
        if (arow < M) av = *(const float4*)(A + (size_t)arow * K + k0 + kA);
        As[kA + 0][mA] = av.x; As[kA + 1][mA] = av.y;
        As[kA + 2][mA] = av.z; As[kA + 3][mA] = av.w;
        *(float4*)(&Bs[kB][nB]) = *(const float4*)(B + (size_t)(k0 + kB) * 256 + bn + nB);
        __syncthreads();
#pragma unroll
        for (int kk = 0; kk < 16; ++kk) {
            const float4 a = *(const float4*)(&As[kk][ty << 2]);
            const float4 b = *(const float4*)(&Bs[kk][tx << 2]);
            acc[0][0] += a.x * b.x; acc[0][1] += a.x * b.y; acc[0][2] += a.x * b.z; acc[0][3] += a.x * b.w;
            acc[1][0] += a.y * b.x; acc[1][1] += a.y * b.y; acc[1][2] += a.y * b.z; acc[1][3] += a.y * b.w;
            acc[2][0] += a.z * b.x; acc[2][1] += a.z * b.y; acc[2][2] += a.z * b.z; acc[2][3] += a.z * b.w;
            acc[3][0] += a.w * b.x; acc[3][1] += a.w * b.y; acc[3][2] += a.w * b.z; acc[3][3] += a.w * b.w;
        }
        __syncthreads();
    }
    const int col = bn + (tx << 2);
#pragma unroll
    for (int i = 0; i < 4; i++) {
        int row = bm + (ty << 2) + i;
        if (row >= M) break;
        float4 o;
        o.x = acc[i][0]; o.y = acc[i][1]; o.z = acc[i][2]; o.w = acc[i][3];
        if (bias) { o.x += bias[col]; o.y += bias[col + 1]; o.z += bias[col + 2]; o.w += bias[col + 3]; }
        *(float4*)(C + (size_t)row * 256 + col) = o;
    }
}

// ---------------- effective attention-projection matrices ----------------
// weff layout: [l(2)][nt(5)][k(256)][col(32)]
// ts (nt=0): cols 0..15 = src roles t=0,2,4,6 (4 heads each); 16..31 = dst roles t=1,3,5,7
// others:    cols 0..3 = src role, 4..7 = dst role, 8..31 = zero
__global__ __launch_bounds__(256) void fill_weff(const float* __restrict__ Wsrc,
                                                 const float* __restrict__ Wdst,
                                                 const float* __restrict__ asrc,
                                                 const float* __restrict__ adst,
                                                 float* __restrict__ weff)
{
    int idx = blockIdx.x * 256 + threadIdx.x;
    if (idx >= 81920) return;
    int col = idx & 31;
    int k   = (idx >> 5) & 255;
    int lnt = idx >> 13;
    int nt  = lnt % 5;
    int l   = lnt / 5;
    bool is_src; int t, h;
    if (nt == 0) {
        if (col < 16) { is_src = true;  t = (col >> 2) * 2;            h = col & 3; }
        else          { is_src = false; t = ((col - 16) >> 2) * 2 + 1; h = col & 3; }
    } else {
        if (col < 4)      { is_src = true;  t = 2 * nt - 1; h = col; }
        else if (col < 8) { is_src = false; t = 2 * nt - 2; h = col - 4; }
        else { weff[idx] = 0.f; return; }
    }
    const float* W = (is_src ? Wsrc : Wdst) + ((size_t)((l * 8 + t) * 256 + k)) * 256 + h * 64;
    const float* a = (is_src ? asrc : adst) + ((size_t)((l * 8 + t) * 4 + h)) * 64;
    float val = 0.f;
    for (int c = 0; c < 64; c++) val += W[c] * a[c];
    weff[idx] = val;
}

// ---------------- es/ed for all roles of all nodes in one pass ----------------
template<int NO>
__device__ __forceinline__ void attnproj_body(const float* __restrict__ xrow,
                                              const float* __restrict__ W,
                                              float* __restrict__ out)
{
    float acc[NO];
#pragma unroll
    for (int j = 0; j < NO; j++) acc[j] = 0.f;
    for (int k = 0; k < 256; k += 4) {
        const float4 xv = *(const float4*)(xrow + k);
#pragma unroll
        for (int j = 0; j < NO; j++) {
            acc[j] += xv.x * W[(k + 0) * 32 + j] + xv.y * W[(k + 1) * 32 + j]
                    + xv.z * W[(k + 2) * 32 + j] + xv.w * W[(k + 3) * 32 + j];
        }
    }
#pragma unroll
    for (int j = 0; j < NO; j++) out[j] = acc[j];
}

__global__ __launch_bounds__(256) void attnproj(const float* __restrict__ x,
                                                const float* __restrict__ weff_l,
                                                float* __restrict__ attn)
{
    int n = blockIdx.x * 256 + threadIdx.x;
    if (n >= NTOT) return;
    int nt = ntype_of(n);
    const float* W = weff_l + nt * 8192;
    if (nt == 0) attnproj_body<32>(x + (size_t)n * 256, W, attn + (size_t)n * 32);
    else         attnproj_body<8> (x + (size_t)n * 256, W, attn + (size_t)n * 32);
}

// ---------------- init new[] with summed per-type biases ----------------
__global__ __launch_bounds__(256) void init_new(float* __restrict__ nb,
                                                const float* __restrict__ bconv_l)
{
    int n = blockIdx.x;
    int c = threadIdx.x;
    int nt = ntype_of(n);
    float b;
    if (nt == 0) b = bconv_l[256 + c] + bconv_l[3 * 256 + c] + bconv_l[5 * 256 + c] + bconv_l[7 * 256 + c];
    else         b = bconv_l[(2 * nt - 2) * 256 + c];
    nb[(size_t)n * 256 + c] = b;
}

// ---------------- edge kernels ----------------
__global__ __launch_bounds__(256) void edge_logits(const int* __restrict__ ei,
                                                   const float* __restrict__ attn,
                                                   float* __restrict__ ebuf,
                                                   unsigned* __restrict__ mbuf,
                                                   int sbase, int soff, int dbase, int doff)
{
    int i = blockIdx.x * 256 + threadIdx.x;
    if (i >= E_N) return;
    int s = ei[i], d = ei[E_N + i];
    const float4 es = *(const float4*)(attn + (size_t)(sbase + s) * 32 + soff);
    const float4 ed = *(const float4*)(attn + (size_t)(dbase + d) * 32 + doff);
    float4 e;
    e.x = lrelu(es.x + ed.x); e.y = lrelu(es.y + ed.y);
    e.z = lrelu(es.z + ed.z); e.w = lrelu(es.w + ed.w);
    *(float4*)(ebuf + (size_t)i * 4) = e;
    atomicMax(mbuf + d * 4 + 0, enc_f(e.x));
    atomicMax(mbuf + d * 4 + 1, enc_f(e.y));
    atomicMax(mbuf + d * 4 + 2, enc_f(e.z));
    atomicMax(mbuf + d * 4 + 3, enc_f(e.w));
}

__global__ __launch_bounds__(256) void edge_exp(const int* __restrict__ ei,
                                                float* __restrict__ ebuf,
                                                const unsigned* __restrict__ mbuf,
                                                float* __restrict__ den)
{
    int i = blockIdx.x * 256 + threadIdx.x;
    if (i >= E_N) return;
    int d = ei[E_N + i];
    float4 e = *(const float4*)(ebuf + (size_t)i * 4);
    e.x = __expf(e.x - dec_f(mbuf[d * 4 + 0]));
    e.y = __expf(e.y - dec_f(mbuf[d * 4 + 1]));
    e.z = __expf(e.z - dec_f(mbuf[d * 4 + 2]));
    e.w = __expf(e.w - dec_f(mbuf[d * 4 + 3]));
    *(float4*)(ebuf + (size_t)i * 4) = e;
    atomAddF(den + d * 4 + 0, e.x);
    atomAddF(den + d * 4 + 1, e.y);
    atomAddF(den + d * 4 + 2, e.z);
    atomAddF(den + d * 4 + 3, e.w);
}

// 64 lanes per edge, 4 channels each (float4), h = lane/16
__global__ __launch_bounds__(256) void scatter_msg(const int* __restrict__ ei,
                                                   const float* __restrict__ ebuf,
                                                   const float* __restrict__ den,
                                                   const float* __restrict__ hs,
                                                   float* __restrict__ nb, int dbase)
{
    int i = blockIdx.x * 4 + (threadIdx.x >> 6);
    int lane = threadIdx.x & 63;
    int s = ei[i], d = ei[E_N + i];
    int h = lane >> 4;
    float alpha = ebuf[(size_t)i * 4 + h] / (den[d * 4 + h] + 1e-16f);
    const float4 hv = *(const float4*)(hs + (size_t)s * 256 + lane * 4);
    float* orow = nb + (size_t)(dbase + d) * 256 + lane * 4;
    atomAddF(orow + 0, alpha * hv.x);
    atomAddF(orow + 1, alpha * hv.y);
    atomAddF(orow + 2, alpha * hv.z);
    atomAddF(orow + 3, alpha * hv.w);
}

__global__ __launch_bounds__(256) void relu_copy(const float4* __restrict__ in,
                                                 float4* __restrict__ out, int n4)
{
    int i = blockIdx.x * 256 + threadIdx.x;
    if (i >= n4) return;
    float4 v = in[i];
    v.x = fmaxf(v.x, 0.f); v.y = fmaxf(v.y, 0.f);
    v.z = fmaxf(v.z, 0.f); v.w = fmaxf(v.w, 0.f);
    out[i] = v;
}

// ---------------- pooling + head ----------------
__global__ __launch_bounds__(256) void colsum_ts(const float* __restrict__ x,
                                                 float* __restrict__ gsum)
{
    int c = threadIdx.x;
    float s = 0.f;
    for (int r = blockIdx.x; r < 50000; r += gridDim.x) s += x[(size_t)r * 256 + c];
    atomAddF(gsum + c, s);
}

__global__ __launch_bounds__(128) void head_k(const float* __restrict__ gsum,
                                              const float* __restrict__ Wc1,
                                              const float* __restrict__ bc1,
                                              const float* __restrict__ Wc2,
                                              const float* __restrict__ bc2,
                                              float* __restrict__ out)
{
    __shared__ float g[256];
    __shared__ float red[128];
    int t = threadIdx.x;
    g[t] = gsum[t] * (1.f / 50000.f);
    g[t + 128] = gsum[t + 128] * (1.f / 50000.f);
    __syncthreads();
    float acc = bc1[t];
    for (int k = 0; k < 256; k++) acc += g[k] * Wc1[k * 128 + t];
    red[t] = fmaxf(acc, 0.f) * Wc2[t];
    __syncthreads();
    for (int sft = 64; sft > 0; sft >>= 1) {
        if (t < sft) red[t] += red[t + sft];
        __syncthreads();
    }
    if (t == 0) out[0] = red[0] + bc2[0];
}

extern "C" void kernel_launch(void* const* d_in, const int* in_sizes, int n_in,
                              void* d_out, int out_size, void* d_ws, size_t ws_size,
                              hipStream_t stream)
{
    const float* ts_x   = (const float*)d_in[0];
    const float* emb[4] = {(const float*)d_in[1], (const float*)d_in[2],
                           (const float*)d_in[3], (const float*)d_in[4]};
    const float* Wp_ts  = (const float*)d_in[5];
    const float* bp_ts  = (const float*)d_in[6];
    const float* Wp_c   = (const float*)d_in[7];
    const float* bp_c   = (const float*)d_in[8];
    const float* Wsrc   = (const float*)d_in[9];
    const float* Wdst   = (const float*)d_in[10];
    const float* asrc   = (const float*)d_in[11];
    const float* adst   = (const float*)d_in[12];
    const float* bconv  = (const float*)d_in[13];
    const float* Wc1    = (const float*)d_in[14];
    const float* bc1    = (const float*)d_in[15];
    const float* Wc2    = (const float*)d_in[16];
    const float* bc2    = (const float*)d_in[17];
    const int* ei[8];
    for (int t = 0; t < 8; t++) ei[t] = (const int*)d_in[18 + t];

    // workspace layout (floats)
    float* x    = (float*)d_ws;            // 84000*256 = 21,504,000
    float* nb   = x    + 21504000;         // 21,504,000
    float* hs   = nb   + 21504000;         // 50000*256 = 12,800,000
    float* attn = hs   + 12800000;         // 84000*32  =  2,688,000
    float* weff = attn + 2688000;          // 2*5*256*32 =     81,920
    float* ebuf = weff + 81920;            // 100000*4  =    400,000
    unsigned* mbuf = (unsigned*)(ebuf + 400000);  // 50000*4 = 200,000
    float* den  = (float*)(mbuf + 200000); // 200,000
    float* gsum = den + 200000;            // 256

    fill_weff<<<320, 256, 0, stream>>>(Wsrc, Wdst, asrc, adst, weff);

    // projections -> x
    gemm_f32<<<dim3(782, 4), 256, 0, stream>>>(ts_x,   Wp_ts,          x,                      bp_ts,      50000, 64);
    gemm_f32<<<dim3(16,  4), 256, 0, stream>>>(emb[0], Wp_c + 0*32768, x + (size_t)50000*256,  bp_c + 0,    1000, 128);
    gemm_f32<<<dim3(313, 4), 256, 0, stream>>>(emb[1], Wp_c + 1*32768, x + (size_t)51000*256,  bp_c + 256, 20000, 128);
    gemm_f32<<<dim3(79,  4), 256, 0, stream>>>(emb[2], Wp_c + 2*32768, x + (size_t)71000*256,  bp_c + 512,  5000, 128);
    gemm_f32<<<dim3(125, 4), 256, 0, stream>>>(emb[3], Wp_c + 3*32768, x + (size_t)76000*256,  bp_c + 768,  8000, 128);

    static const int stype[8] = {0, 1, 0, 2, 0, 3, 0, 4};
    static const int dtype[8] = {1, 0, 2, 0, 3, 0, 4, 0};
    static const int base_[5] = {0, 50000, 51000, 71000, 76000};
    static const int size_[5] = {50000, 1000, 20000, 5000, 8000};

    for (int l = 0; l < 2; ++l) {
        attnproj<<<329, 256, 0, stream>>>(x, weff + l * 5 * 8192, attn);
        init_new<<<84000, 256, 0, stream>>>(nb, bconv + l * 2048);
        for (int t = 0; t < 8; t++) {
            const int st = stype[t], dt = dtype[t];
            const int Ns = size_[st], Nd = size_[dt];
            const int sbase = base_[st], dbase = base_[dt];
            const int soff = (st == 0) ? 2 * t : 0;
            const int doff = (dt == 0) ? (16 + 2 * (t - 1)) : 4;
            gemm_f32<<<dim3((Ns + 63) / 64, 4), 256, 0, stream>>>(
                x + (size_t)sbase * 256, Wsrc + (size_t)(l * 8 + t) * 65536, hs, nullptr, Ns, 256);
            hipMemsetAsync(mbuf, 0, (size_t)Nd * 4 * sizeof(unsigned), stream);
            hipMemsetAsync(den,  0, (size_t)Nd * 4 * sizeof(float), stream);
            edge_logits<<<391, 256, 0, stream>>>(ei[t], attn, ebuf, mbuf, sbase, soff, dbase, doff);
            edge_exp<<<391, 256, 0, stream>>>(ei[t], ebuf, mbuf, den);
            scatter_msg<<<25000, 256, 0, stream>>>(ei[t], ebuf, den, hs, nb, dbase);
        }
        relu_copy<<<21000, 256, 0, stream>>>((const float4*)nb, (float4*)x, 5376000);
    }

    hipMemsetAsync(gsum, 0, 256 * sizeof(float), stream);
    colsum_ts<<<256, 256, 0, stream>>>(x, gsum);
    head_k<<<1, 128, 0, stream>>>(gsum, Wc1, bc1, Wc2, bc2, (float*)d_out);
}

// Round 2
// 1561.033 us; speedup vs baseline: 5.0339x; 5.0339x over previous
//
#include <hip/hip_runtime.h>

#define E_N 100000
#define NTOT 84000
#define NDST 234000   // concatenated per-type dst index space

// node types: 0=ts 1=vital 2=diag 3=med 4=proc
__device__ __forceinline__ int ntype_of(int n) {
    if (n < 50000) return 0;
    if (n < 51000) return 1;
    if (n < 71000) return 2;
    if (n < 76000) return 3;
    return 4;
}

__device__ __forceinline__ void atomAddF(float* p, float v) {
    unsafeAtomicAdd(p, v);   // native global_atomic_add_f32 on gfx950
}

__device__ __forceinline__ float lrelu(float v) { return v >= 0.f ? v : 0.2f * v; }

// CSR dst-space bases per edge type t (dst sizes: 1000,50000,20000,50000,5000,50000,8000,50000)
__constant__ int c_tbase[8] = {0, 1000, 51000, 71000, 121000, 126000, 176000, 184000};

struct EI8 { const int* p[8]; };

// ---------------- fp32 GEMM: C[M x 256] = A[M x K] @ B[K x 256] (+bias) ----------------
__global__ __launch_bounds__(256) void gemm_f32(const float* __restrict__ A,
                                                const float* __restrict__ B,
                                                float* __restrict__ C,
                                                const float* __restrict__ bias,
                                                int M, int K)
{
    __shared__ __align__(16) float As[16][68];
    __shared__ __align__(16) float Bs[16][68];
    const int tid = threadIdx.x;
    const int bm = blockIdx.x * 64;
    const int bn = blockIdx.y * 64;
    const int ty = tid >> 4, tx = tid & 15;
    const int mA = tid >> 2, kA = (tid & 3) << 2;
    const int kB = tid >> 4, nB = (tid & 15) << 2;
    float acc[4][4] = {};
    for (int k0 = 0; k0 < K; k0 += 16) {
        float4 av = make_float4(0.f, 0.f, 0.f, 0.f);
        int arow = bm + mA;
        if (arow < M) av = *(const float4*)(A + (size_t)arow * K + k0 + kA);
        As[kA + 0][mA] = av.x; As[kA + 1][mA] = av.y;
        As[kA + 2][mA] = av.z; As[kA + 3][mA] = av.w;
        *(float4*)(&Bs[kB][nB]) = *(const float4*)(B + (size_t)(k0 + kB) * 256 + bn + nB);
        __syncthreads();
#pragma unroll
        for (int kk = 0; kk < 16; ++kk) {
            const float4 a = *(const float4*)(&As[kk][ty << 2]);
            const float4 b = *(const float4*)(&Bs[kk][tx << 2]);
            acc[0][0] += a.x * b.x; acc[0][1] += a.x * b.y; acc[0][2] += a.x * b.z; acc[0][3] += a.x * b.w;
            acc[1][0] += a.y * b.x; acc[1][1] += a.y * b.y; acc[1][2] += a.y * b.z; acc[1][3] += a.y * b.w;
            acc[2][0] += a.z * b.x; acc[2][1] += a.z * b.y; acc[2][2] += a.z * b.z; acc[2][3] += a.z * b.w;
            acc[3][0] += a.w * b.x; acc[3][1] += a.w * b.y; acc[3][2] += a.w * b.z; acc[3][3] += a.w * b.w;
        }
        __syncthreads();
    }
    const int col = bn + (tx << 2);
#pragma unroll
    for (int i = 0; i < 4; i++) {
        int row = bm + (ty << 2) + i;
        if (row >= M) break;
        float4 o;
        o.x = acc[i][0]; o.y = acc[i][1]; o.z = acc[i][2]; o.w = acc[i][3];
        if (bias) { o.x += bias[col]; o.y += bias[col + 1]; o.z += bias[col + 2]; o.w += bias[col + 3]; }
        *(float4*)(C + (size_t)row * 256 + col) = o;
    }
}

// ---------------- effective attention-projection matrices ----------------
// weff layout: [l(2)][nt(5)][k(256)][col(32)]
// ts (nt=0): cols 0..15 = src roles t=0,2,4,6 ; 16..31 = dst roles t=1,3,5,7
// others:    cols 0..3 = src role, 4..7 = dst role, 8..31 = zero
__global__ __launch_bounds__(256) void fill_weff(const float* __restrict__ Wsrc,
                                                 const float* __restrict__ Wdst,
                                                 const float* __restrict__ asrc,
                                                 const float* __restrict__ adst,
                                                 float* __restrict__ weff)
{
    int idx = blockIdx.x * 256 + threadIdx.x;
    if (idx >= 81920) return;
    int col = idx & 31;
    int k   = (idx >> 5) & 255;
    int lnt = idx >> 13;
    int nt  = lnt % 5;
    int l   = lnt / 5;
    bool is_src; int t, h;
    if (nt == 0) {
        if (col < 16) { is_src = true;  t = (col >> 2) * 2;            h = col & 3; }
        else          { is_src = false; t = ((col - 16) >> 2) * 2 + 1; h = col & 3; }
    } else {
        if (col < 4)      { is_src = true;  t = 2 * nt - 1; h = col; }
        else if (col < 8) { is_src = false; t = 2 * nt - 2; h = col - 4; }
        else { weff[idx] = 0.f; return; }
    }
    const float* W = (is_src ? Wsrc : Wdst) + ((size_t)((l * 8 + t) * 256 + k)) * 256 + h * 64;
    const float* a = (is_src ? asrc : adst) + ((size_t)((l * 8 + t) * 4 + h)) * 64;
    float val = 0.f;
    for (int c = 0; c < 64; c++) val += W[c] * a[c];
    weff[idx] = val;
}

// ---------------- attn projections: ts nodes 32 cols, compact nodes 8 cols ----------------
template<int NO>
__device__ __forceinline__ void attnproj_body(const float* __restrict__ xrow,
                                              const float* __restrict__ W,
                                              float* __restrict__ out)
{
    float acc[NO];
#pragma unroll
    for (int j = 0; j < NO; j++) acc[j] = 0.f;
    for (int k = 0; k < 256; k += 4) {
        const float4 xv = *(const float4*)(xrow + k);
#pragma unroll
        for (int j = 0; j < NO; j++) {
            acc[j] += xv.x * W[(k + 0) * 32 + j] + xv.y * W[(k + 1) * 32 + j]
                    + xv.z * W[(k + 2) * 32 + j] + xv.w * W[(k + 3) * 32 + j];
        }
    }
#pragma unroll
    for (int j = 0; j < NO; j++) out[j] = acc[j];
}

__global__ __launch_bounds__(256) void attnproj(const float* __restrict__ x,
                                                const float* __restrict__ weff_l,
                                                float* __restrict__ attnT,
                                                float* __restrict__ attnC)
{
    int n = blockIdx.x * 256 + threadIdx.x;
    if (n >= NTOT) return;
    if (n < 50000) {
        attnproj_body<32>(x + (size_t)n * 256, weff_l, attnT + (size_t)n * 32);
    } else {
        int nt = ntype_of(n);
        attnproj_body<8>(x + (size_t)n * 256, weff_l + nt * 8192, attnC + (size_t)(n - 50000) * 8);
    }
}

// ---------------- CSR build ----------------
__global__ __launch_bounds__(256) void count_k(EI8 ei, int* __restrict__ cnt)
{
    int g = blockIdx.x * 256 + threadIdx.x;
    if (g >= 8 * E_N) return;
    int t = g / E_N;
    int i = g - t * E_N;
    int d = ei.p[t][E_N + i];
    atomicAdd(&cnt[c_tbase[t] + d], 1);
}

__global__ __launch_bounds__(256) void scanA(const int* __restrict__ cnt,
                                             int* __restrict__ rowptr,
                                             int* __restrict__ bsum)
{
    __shared__ int sd[256];
    int b = blockIdx.x, t = threadIdx.x;
    int base = b * 1024 + t * 4;
    int v0 = 0, v1 = 0, v2 = 0, v3 = 0;
    if (base + 0 < NDST) v0 = cnt[base + 0];
    if (base + 1 < NDST) v1 = cnt[base + 1];
    if (base + 2 < NDST) v2 = cnt[base + 2];
    if (base + 3 < NDST) v3 = cnt[base + 3];
    int s = v0 + v1 + v2 + v3;
    sd[t] = s;
    __syncthreads();
    for (int off = 1; off < 256; off <<= 1) {
        int x = 0;
        if (t >= off) x = sd[t - off];
        __syncthreads();
        if (t >= off) sd[t] += x;
        __syncthreads();
    }
    int run = sd[t] - s;  // exclusive prefix
    if (t == 255) bsum[b] = sd[255];
    if (base + 0 < NDST) rowptr[base + 0] = run;          run += v0;
    if (base + 1 < NDST) rowptr[base + 1] = run;          run += v1;
    if (base + 2 < NDST) rowptr[base + 2] = run;          run += v2;
    if (base + 3 < NDST) rowptr[base + 3] = run;
}

__global__ __launch_bounds__(256) void scanB(int* __restrict__ bsum, int nb)
{
    __shared__ int sd[256];
    int t = threadIdx.x;
    int v = (t < nb) ? bsum[t] : 0;
    sd[t] = v;
    __syncthreads();
    for (int off = 1; off < 256; off <<= 1) {
        int x = 0;
        if (t >= off) x = sd[t - off];
        __syncthreads();
        if (t >= off) sd[t] += x;
        __syncthreads();
    }
    if (t < nb) bsum[t] = sd[t] - v;  // exclusive
}

__global__ __launch_bounds__(256) void scanC(int* __restrict__ rowptr,
                                             const int* __restrict__ bsum,
                                             int* __restrict__ cursor)
{
    int b = blockIdx.x, t = threadIdx.x;
    int off = bsum[b];
    int base = b * 1024 + t * 4;
#pragma unroll
    for (int j = 0; j < 4; j++) {
        int i = base + j;
        if (i < NDST) {
            int r = rowptr[i] + off;
            rowptr[i] = r;
            cursor[i] = r;
        }
    }
    if (b == 0 && t == 0) rowptr[NDST] = 8 * E_N;
}

__global__ __launch_bounds__(256) void place_k(EI8 ei, int* __restrict__ cursor,
                                               int* __restrict__ ssrc)
{
    int g = blockIdx.x * 256 + threadIdx.x;
    if (g >= 8 * E_N) return;
    int t = g / E_N;
    int i = g - t * E_N;
    int d = ei.p[t][E_N + i];
    int s = ei.p[t][i];
    int pos = atomicAdd(&cursor[c_tbase[t] + d], 1);
    ssrc[pos] = s;
}

// ---------------- fused aggregation: all 4 compact->ts types, one wave per ts node ----------------
__global__ __launch_bounds__(256) void agg_ts(const float* __restrict__ attnT,
                                              const float* __restrict__ attnC,
                                              const float* __restrict__ hsc,   // global-row-indexed (xout base)
                                              const int* __restrict__ rowptr,
                                              const int* __restrict__ ssrc,
                                              const float* __restrict__ bconv_l,
                                              float* __restrict__ xout)
{
    int d = blockIdx.x * 4 + (threadIdx.x >> 6);   // grid = 12500 exact
    int lane = threadIdx.x & 63;
    int h = lane >> 4;
    int ch = (h << 6) | ((lane & 15) << 2);
    const int sb4[4]   = {50000, 51000, 71000, 76000}; // hs global row base per src type
    const int co4[4]   = {0, 1000, 21000, 26000};      // attnC row base
    const int tb4[4]   = {1000, 71000, 126000, 184000};// CSR base (types 1,3,5,7)
    const int doff4[4] = {16, 20, 24, 28};
    const int bo4[4]   = {256, 768, 1280, 1792};       // bconv offsets for t=1,3,5,7
    float ax = 0.f, ay = 0.f, az = 0.f, aw = 0.f;
#pragma unroll
    for (int q = 0; q < 4; q++) {
        const float* b = bconv_l + bo4[q] + ch;
        ax += b[0]; ay += b[1]; az += b[2]; aw += b[3];
    }
#pragma unroll
    for (int q = 0; q < 4; q++) {
        int r0 = rowptr[tb4[q] + d], r1 = rowptr[tb4[q] + d + 1];
        float ed = attnT[(size_t)d * 32 + doff4[q] + h];
        float m = -1e30f;
        for (int e = r0; e < r1; e++) {
            int s = ssrc[e];
            float es = attnC[(size_t)(co4[q] + s) * 8 + h];
            m = fmaxf(m, lrelu(es + ed));
        }
        float den = 0.f, sx = 0.f, sy = 0.f, sz = 0.f, sw = 0.f;
        for (int e = r0; e < r1; e++) {
            int s = ssrc[e];
            float es = attnC[(size_t)(co4[q] + s) * 8 + h];
            float ex = __expf(lrelu(es + ed) - m);
            den += ex;
            const float4 hv = *(const float4*)(hsc + (size_t)(sb4[q] + s) * 256 + ch);
            sx += ex * hv.x; sy += ex * hv.y; sz += ex * hv.z; sw += ex * hv.w;
        }
        float inv = 1.f / (den + 1e-16f);
        ax += sx * inv; ay += sy * inv; az += sz * inv; aw += sw * inv;
    }
    float4 o;
    o.x = fmaxf(ax, 0.f); o.y = fmaxf(ay, 0.f);
    o.z = fmaxf(az, 0.f); o.w = fmaxf(aw, 0.f);
    *(float4*)(xout + (size_t)d * 256 + ch) = o;
}

// ---------------- aggregation for one ts->compact type, one wave per compact dst ----------------
__global__ __launch_bounds__(256) void agg_compact(const float* __restrict__ attnT,
                                                   const float* __restrict__ attnC,
                                                   const float* __restrict__ hsts,
                                                   const int* __restrict__ rowptr_t, // + CSR base
                                                   const int* __restrict__ ssrc,
                                                   const float* __restrict__ bias,   // bconv_l + t*256
                                                   float* __restrict__ xout_rows,    // xout + dbase*256
                                                   int Nd, int soff, int cobase)
{
    int d = blockIdx.x * 4 + (threadIdx.x >> 6);
    if (d >= Nd) return;
    int lane = threadIdx.x & 63;
    int h = lane >> 4;
    int ch = (h << 6) | ((lane & 15) << 2);
    int r0 = rowptr_t[d], r1 = rowptr_t[d + 1];
    float ed = attnC[(size_t)(cobase + d) * 8 + 4 + h];
    float m = -1e30f;
    for (int e = r0; e < r1; e++) {
        int s = ssrc[e];
        float es = attnT[(size_t)s * 32 + soff + h];
        m = fmaxf(m, lrelu(es + ed));
    }
    float den = 0.f, sx = 0.f, sy = 0.f, sz = 0.f, sw = 0.f;
    for (int e = r0; e < r1; e++) {
        int s = ssrc[e];
        float es = attnT[(size_t)s * 32 + soff + h];
        float ex = __expf(lrelu(es + ed) - m);
        den += ex;
        const float4 hv = *(const float4*)(hsts + (size_t)s * 256 + ch);
        sx += ex * hv.x; sy += ex * hv.y; sz += ex * hv.z; sw += ex * hv.w;
    }
    float inv = 1.f / (den + 1e-16f);
    const float* b = bias + ch;
    float4 o;
    o.x = fmaxf(b[0] + sx * inv, 0.f);
    o.y = fmaxf(b[1] + sy * inv, 0.f);
    o.z = fmaxf(b[2] + sz * inv, 0.f);
    o.w = fmaxf(b[3] + sw * inv, 0.f);
    *(float4*)(xout_rows + (size_t)d * 256 + ch) = o;
}

// ---------------- pooling + head ----------------
__global__ __launch_bounds__(256) void colsum_ts(const float* __restrict__ x,
                                                 float* __restrict__ gsum)
{
    int c = threadIdx.x;
    float s = 0.f;
    for (int r = blockIdx.x; r < 50000; r += gridDim.x) s += x[(size_t)r * 256 + c];
    atomAddF(gsum + c, s);
}

__global__ __launch_bounds__(128) void head_k(const float* __restrict__ gsum,
                                              const float* __restrict__ Wc1,
                                              const float* __restrict__ bc1,
                                              const float* __restrict__ Wc2,
                                              const float* __restrict__ bc2,
                                              float* __restrict__ out)
{
    __shared__ float g[256];
    __shared__ float red[128];
    int t = threadIdx.x;
    g[t] = gsum[t] * (1.f / 50000.f);
    g[t + 128] = gsum[t + 128] * (1.f / 50000.f);
    __syncthreads();
    float acc = bc1[t];
    for (int k = 0; k < 256; k++) acc += g[k] * Wc1[k * 128 + t];
    red[t] = fmaxf(acc, 0.f) * Wc2[t];
    __syncthreads();
    for (int sft = 64; sft > 0; sft >>= 1) {
        if (t < sft) red[t] += red[t + sft];
        __syncthreads();
    }
    if (t == 0) out[0] = red[0] + bc2[0];
}

extern "C" void kernel_launch(void* const* d_in, const int* in_sizes, int n_in,
                              void* d_out, int out_size, void* d_ws, size_t ws_size,
                              hipStream_t stream)
{
    const float* ts_x   = (const float*)d_in[0];
    const float* emb[4] = {(const float*)d_in[1], (const float*)d_in[2],
                           (const float*)d_in[3], (const float*)d_in[4]};
    const float* Wp_ts  = (const float*)d_in[5];
    const float* bp_ts  = (const float*)d_in[6];
    const float* Wp_c   = (const float*)d_in[7];
    const float* bp_c   = (const float*)d_in[8];
    const float* Wsrc   = (const float*)d_in[9];
    const float* Wdst   = (const float*)d_in[10];
    const float* asrc   = (const float*)d_in[11];
    const float* adst   = (const float*)d_in[12];
    const float* bconv  = (const float*)d_in[13];
    const float* Wc1    = (const float*)d_in[14];
    const float* bc1    = (const float*)d_in[15];
    const float* Wc2    = (const float*)d_in[16];
    const float* bc2    = (const float*)d_in[17];
    EI8 ei;
    for (int t = 0; t < 8; t++) ei.p[t] = (const int*)d_in[18 + t];

    // workspace layout
    float* x0    = (float*)d_ws;           // 21,504,000 floats
    float* x1    = x0    + 21504000;       // 21,504,000
    float* hsts  = x1    + 21504000;       // 12,800,000 (ts-source hs; also aliased as CSR cursor early)
    float* attnT = hsts  + 12800000;       // 50000*32 = 1,600,000
    float* attnC = attnT + 1600000;        // 34000*8  =   272,000
    float* weff  = attnC + 272000;         // 81,920
    float* gsum  = weff  + 81920;          // 256
    int* rowptr  = (int*)(gsum + 256);     // NDST+1 (+pad)
    int* bsum    = rowptr + 234004;        // 232 (reuse head of ssrc region? keep separate small)
    int* ssrc    = bsum + 256;             // 800,000
    int* cursor  = (int*)hsts;             // alias: CSR build finishes before hsts GEMMs

    // ---- CSR build (shared by both layers) ----
    hipMemsetAsync(cursor, 0, NDST * sizeof(int), stream);
    count_k<<<3125, 256, 0, stream>>>(ei, cursor);
    scanA<<<229, 256, 0, stream>>>(cursor, rowptr, bsum);
    scanB<<<1, 256, 0, stream>>>(bsum, 229);
    scanC<<<229, 256, 0, stream>>>(rowptr, bsum, cursor);
    place_k<<<3125, 256, 0, stream>>>(ei, cursor, ssrc);

    fill_weff<<<320, 256, 0, stream>>>(Wsrc, Wdst, asrc, adst, weff);

    // ---- input projections -> x0 ----
    gemm_f32<<<dim3(782, 4), 256, 0, stream>>>(ts_x,   Wp_ts,          x0,                     bp_ts,      50000, 64);
    gemm_f32<<<dim3(16,  4), 256, 0, stream>>>(emb[0], Wp_c + 0*32768, x0 + (size_t)50000*256, bp_c + 0,    1000, 128);
    gemm_f32<<<dim3(313, 4), 256, 0, stream>>>(emb[1], Wp_c + 1*32768, x0 + (size_t)51000*256, bp_c + 256, 20000, 128);
    gemm_f32<<<dim3(79,  4), 256, 0, stream>>>(emb[2], Wp_c + 2*32768, x0 + (size_t)71000*256, bp_c + 512,  5000, 128);
    gemm_f32<<<dim3(125, 4), 256, 0, stream>>>(emb[3], Wp_c + 3*32768, x0 + (size_t)76000*256, bp_c + 768,  8000, 128);

    for (int l = 0; l < 2; ++l) {
        float* xin  = (l == 0) ? x0 : x1;
        float* xout = (l == 0) ? x1 : x0;
        const float* bconv_l = bconv + l * 2048;

        attnproj<<<329, 256, 0, stream>>>(xin, weff + l * 40960, attnT, attnC);

        // hs for compact sources (types 1,3,5,7) -> xout compact region (global-row aligned)
        gemm_f32<<<dim3(16,  4), 256, 0, stream>>>(xin + (size_t)50000*256, Wsrc + (size_t)(l*8+1)*65536,
                                                   xout + (size_t)50000*256, nullptr,  1000, 256);
        gemm_f32<<<dim3(313, 4), 256, 0, stream>>>(xin + (size_t)51000*256, Wsrc + (size_t)(l*8+3)*65536,
                                                   xout + (size_t)51000*256, nullptr, 20000, 256);
        gemm_f32<<<dim3(79,  4), 256, 0, stream>>>(xin + (size_t)71000*256, Wsrc + (size_t)(l*8+5)*65536,
                                                   xout + (size_t)71000*256, nullptr,  5000, 256);
        gemm_f32<<<dim3(125, 4), 256, 0, stream>>>(xin + (size_t)76000*256, Wsrc + (size_t)(l*8+7)*65536,
                                                   xout + (size_t)76000*256, nullptr,  8000, 256);

        // fused softmax+gather aggregation for all 4 types into ts rows of xout (reads xout compact)
        agg_ts<<<12500, 256, 0, stream>>>(attnT, attnC, xout, rowptr, ssrc, bconv_l, xout);

        if (l == 0) {
            // ts -> compact (only needed in layer 1; layer-2 compact outputs are dead)
            static const int tlist[4]  = {0, 2, 4, 6};
            static const int dbase4[4] = {50000, 51000, 71000, 76000};
            static const int Nd4[4]    = {1000, 20000, 5000, 8000};
            static const int csr4[4]   = {0, 51000, 121000, 176000};
            static const int co4[4]    = {0, 1000, 21000, 26000};
            for (int q = 0; q < 4; q++) {
                int t = tlist[q];
                gemm_f32<<<dim3(782, 4), 256, 0, stream>>>(xin, Wsrc + (size_t)(l*8+t)*65536,
                                                           hsts, nullptr, 50000, 256);
                agg_compact<<<(Nd4[q] + 3) / 4, 256, 0, stream>>>(
                    attnT, attnC, hsts, rowptr + csr4[q], ssrc, bconv_l + t * 256,
                    xout + (size_t)dbase4[q] * 256, Nd4[q], 2 * t, co4[q]);
            }
        }
    }

    hipMemsetAsync(gsum, 0, 256 * sizeof(float), stream);
    colsum_ts<<<256, 256, 0, stream>>>(x0, gsum);
    head_k<<<1, 128, 0, stream>>>(gsum, Wc1, bc1, Wc2, bc2, (float*)d_out);
}

// Round 3
// 969.129 us; speedup vs baseline: 8.1084x; 1.6108x over previous
//
#include <hip/hip_runtime.h>

#define E_N 100000
#define NTOT 84000
#define NDST 234000   // concatenated per-type dst index space

__device__ __forceinline__ void atomAddF(float* p, float v) {
    unsafeAtomicAdd(p, v);
}

__device__ __forceinline__ float lrelu(float v) { return v >= 0.f ? v : 0.2f * v; }

// CSR dst-space bases per edge type t (dst sizes: 1000,50000,20000,50000,5000,50000,8000,50000)
__constant__ int c_tbase[8] = {0, 1000, 51000, 71000, 121000, 126000, 176000, 184000};

struct EI8 { const int* p[8]; };

// ---------------- batched fp32 GEMM: C[M x 256] = A[M x K] @ B[K x 256] (+bias, +relu) ----
// 128x128 tile (grid.y=2 covers N=256), 8x8 micro-tile, BK=16, 256 threads.
struct GJob { const float* A; const float* B; float* C; const float* bias; int M; int K; int relu; int pad; };
struct GBatch { GJob j[8]; };

__global__ __launch_bounds__(256) void gemm128(GBatch batch)
{
    const GJob jb = batch.j[blockIdx.z];
    const int bm = blockIdx.x * 128;
    if (bm >= jb.M) return;
    const int bn = blockIdx.y * 128;
    const int M = jb.M, K = jb.K;

    __shared__ __align__(16) float As[16][132];
    __shared__ __align__(16) float Bs[16][132];

    const int tid  = threadIdx.x;
    const int tm   = tid >> 4;          // 0..15 : rows tm*8..+7
    const int tn4  = (tid & 15) * 4;    // cols tn4..+3 and 64+tn4..+3
    const int arow = tid >> 1;          // 0..127
    const int ak   = (tid & 1) * 8;     // 0 or 8
    const int bk   = tid >> 4;          // 0..15
    const int bc   = (tid & 15) * 8;    // 0..120

    float4 acc0[8], acc1[8];
#pragma unroll
    for (int r = 0; r < 8; r++) {
        acc0[r] = make_float4(0.f, 0.f, 0.f, 0.f);
        acc1[r] = make_float4(0.f, 0.f, 0.f, 0.f);
    }

    for (int k0 = 0; k0 < K; k0 += 16) {
        float4 a0 = make_float4(0.f, 0.f, 0.f, 0.f), a1 = a0;
        if (bm + arow < M) {
            const float* ap = jb.A + (size_t)(bm + arow) * K + k0 + ak;
            a0 = *(const float4*)(ap);
            a1 = *(const float4*)(ap + 4);
        }
        As[ak + 0][arow] = a0.x; As[ak + 1][arow] = a0.y;
        As[ak + 2][arow] = a0.z; As[ak + 3][arow] = a0.w;
        As[ak + 4][arow] = a1.x; As[ak + 5][arow] = a1.y;
        As[ak + 6][arow] = a1.z; As[ak + 7][arow] = a1.w;
        const float* bp = jb.B + (size_t)(k0 + bk) * 256 + bn + bc;
        *(float4*)(&Bs[bk][bc])     = *(const float4*)(bp);
        *(float4*)(&Bs[bk][bc + 4]) = *(const float4*)(bp + 4);
        __syncthreads();
#pragma unroll
        for (int kk = 0; kk < 16; ++kk) {
            const float4 av0 = *(const float4*)(&As[kk][tm * 8]);
            const float4 av1 = *(const float4*)(&As[kk][tm * 8 + 4]);
            const float4 bv0 = *(const float4*)(&Bs[kk][tn4]);
            const float4 bv1 = *(const float4*)(&Bs[kk][tn4 + 64]);
            float a_[8] = {av0.x, av0.y, av0.z, av0.w, av1.x, av1.y, av1.z, av1.w};
#pragma unroll
            for (int r = 0; r < 8; r++) {
                acc0[r].x += a_[r] * bv0.x; acc0[r].y += a_[r] * bv0.y;
                acc0[r].z += a_[r] * bv0.z; acc0[r].w += a_[r] * bv0.w;
                acc1[r].x += a_[r] * bv1.x; acc1[r].y += a_[r] * bv1.y;
                acc1[r].z += a_[r] * bv1.z; acc1[r].w += a_[r] * bv1.w;
            }
        }
        __syncthreads();
    }

    const int col0 = bn + tn4;
    const int col1 = bn + tn4 + 64;
    float4 bi0 = make_float4(0.f, 0.f, 0.f, 0.f), bi1 = bi0;
    if (jb.bias) {
        bi0 = *(const float4*)(jb.bias + col0);
        bi1 = *(const float4*)(jb.bias + col1);
    }
#pragma unroll
    for (int r = 0; r < 8; r++) {
        int row = bm + tm * 8 + r;
        if (row >= M) break;
        float4 o0 = acc0[r], o1 = acc1[r];
        o0.x += bi0.x; o0.y += bi0.y; o0.z += bi0.z; o0.w += bi0.w;
        o1.x += bi1.x; o1.y += bi1.y; o1.z += bi1.z; o1.w += bi1.w;
        if (jb.relu) {
            o0.x = fmaxf(o0.x, 0.f); o0.y = fmaxf(o0.y, 0.f);
            o0.z = fmaxf(o0.z, 0.f); o0.w = fmaxf(o0.w, 0.f);
            o1.x = fmaxf(o1.x, 0.f); o1.y = fmaxf(o1.y, 0.f);
            o1.z = fmaxf(o1.z, 0.f); o1.w = fmaxf(o1.w, 0.f);
        }
        *(float4*)(jb.C + (size_t)row * 256 + col0) = o0;
        *(float4*)(jb.C + (size_t)row * 256 + col1) = o1;
    }
}

// ---------------- effective attention-projection matrices ----------------
// weff layout: [l(2)][nt(5)][k(256)][col(32)]
__global__ __launch_bounds__(256) void fill_weff(const float* __restrict__ Wsrc,
                                                 const float* __restrict__ Wdst,
                                                 const float* __restrict__ asrc,
                                                 const float* __restrict__ adst,
                                                 float* __restrict__ weff)
{
    int idx = blockIdx.x * 256 + threadIdx.x;
    if (idx >= 81920) return;
    int col = idx & 31;
    int k   = (idx >> 5) & 255;
    int lnt = idx >> 13;
    int nt  = lnt % 5;
    int l   = lnt / 5;
    bool is_src; int t, h;
    if (nt == 0) {
        if (col < 16) { is_src = true;  t = (col >> 2) * 2;            h = col & 3; }
        else          { is_src = false; t = ((col - 16) >> 2) * 2 + 1; h = col & 3; }
    } else {
        if (col < 4)      { is_src = true;  t = 2 * nt - 1; h = col; }
        else if (col < 8) { is_src = false; t = 2 * nt - 2; h = col - 4; }
        else { weff[idx] = 0.f; return; }
    }
    const float* W = (is_src ? Wsrc : Wdst) + ((size_t)((l * 8 + t) * 256 + k)) * 256 + h * 64;
    const float* a = (is_src ? asrc : adst) + ((size_t)((l * 8 + t) * 4 + h)) * 64;
    float val = 0.f;
    for (int c = 0; c < 64; c++) val += W[c] * a[c];
    weff[idx] = val;
}

// ---------------- attn projections ----------------
template<int NO>
__device__ __forceinline__ void attnproj_body(const float* __restrict__ xrow,
                                              const float* __restrict__ W,
                                              float* __restrict__ out)
{
    float acc[NO];
#pragma unroll
    for (int j = 0; j < NO; j++) acc[j] = 0.f;
    for (int k = 0; k < 256; k += 4) {
        const float4 xv = *(const float4*)(xrow + k);
#pragma unroll
        for (int j = 0; j < NO; j++) {
            acc[j] += xv.x * W[(k + 0) * 32 + j] + xv.y * W[(k + 1) * 32 + j]
                    + xv.z * W[(k + 2) * 32 + j] + xv.w * W[(k + 3) * 32 + j];
        }
    }
#pragma unroll
    for (int j = 0; j < NO; j++) out[j] = acc[j];
}

__global__ __launch_bounds__(256) void attnproj(const float* __restrict__ x,
                                                const float* __restrict__ weff_l,
                                                float* __restrict__ attnT,
                                                float* __restrict__ attnC)
{
    int n = blockIdx.x * 256 + threadIdx.x;
    if (n >= NTOT) return;
    if (n < 50000) {
        attnproj_body<32>(x + (size_t)n * 256, weff_l, attnT + (size_t)n * 32);
    } else {
        int nt = (n < 51000) ? 1 : (n < 71000) ? 2 : (n < 76000) ? 3 : 4;
        attnproj_body<8>(x + (size_t)n * 256, weff_l + nt * 8192, attnC + (size_t)(n - 50000) * 8);
    }
}

// ---------------- CSR build ----------------
__global__ __launch_bounds__(256) void count_k(EI8 ei, int* __restrict__ cnt)
{
    int g = blockIdx.x * 256 + threadIdx.x;
    if (g >= 8 * E_N) return;
    int t = g / E_N;
    int i = g - t * E_N;
    int d = ei.p[t][E_N + i];
    atomicAdd(&cnt[c_tbase[t] + d], 1);
}

__global__ __launch_bounds__(256) void scanA(const int* __restrict__ cnt,
                                             int* __restrict__ rowptr,
                                             int* __restrict__ bsum)
{
    __shared__ int sd[256];
    int b = blockIdx.x, t = threadIdx.x;
    int base = b * 1024 + t * 4;
    int v0 = 0, v1 = 0, v2 = 0, v3 = 0;
    if (base + 0 < NDST) v0 = cnt[base + 0];
    if (base + 1 < NDST) v1 = cnt[base + 1];
    if (base + 2 < NDST) v2 = cnt[base + 2];
    if (base + 3 < NDST) v3 = cnt[base + 3];
    int s = v0 + v1 + v2 + v3;
    sd[t] = s;
    __syncthreads();
    for (int off = 1; off < 256; off <<= 1) {
        int x = 0;
        if (t >= off) x = sd[t - off];
        __syncthreads();
        if (t >= off) sd[t] += x;
        __syncthreads();
    }
    int run = sd[t] - s;
    if (t == 255) bsum[b] = sd[255];
    if (base + 0 < NDST) rowptr[base + 0] = run;          run += v0;
    if (base + 1 < NDST) rowptr[base + 1] = run;          run += v1;
    if (base + 2 < NDST) rowptr[base + 2] = run;          run += v2;
    if (base + 3 < NDST) rowptr[base + 3] = run;
}

__global__ __launch_bounds__(256) void scanB(int* __restrict__ bsum, int nb)
{
    __shared__ int sd[256];
    int t = threadIdx.x;
    int v = (t < nb) ? bsum[t] : 0;
    sd[t] = v;
    __syncthreads();
    for (int off = 1; off < 256; off <<= 1) {
        int x = 0;
        if (t >= off) x = sd[t - off];
        __syncthreads();
        if (t >= off) sd[t] += x;
        __syncthreads();
    }
    if (t < nb) bsum[t] = sd[t] - v;
}

__global__ __launch_bounds__(256) void scanC(int* __restrict__ rowptr,
                                             const int* __restrict__ bsum,
                                             int* __restrict__ cursor)
{
    int b = blockIdx.x, t = threadIdx.x;
    int off = bsum[b];
    int base = b * 1024 + t * 4;
#pragma unroll
    for (int j = 0; j < 4; j++) {
        int i = base + j;
        if (i < NDST) {
            int r = rowptr[i] + off;
            rowptr[i] = r;
            cursor[i] = r;
        }
    }
    if (b == 0 && t == 0) rowptr[NDST] = 8 * E_N;
}

__global__ __launch_bounds__(256) void place_k(EI8 ei, int* __restrict__ cursor,
                                               int* __restrict__ ssrc)
{
    int g = blockIdx.x * 256 + threadIdx.x;
    if (g >= 8 * E_N) return;
    int t = g / E_N;
    int i = g - t * E_N;
    int d = ei.p[t][E_N + i];
    int s = ei.p[t][i];
    int pos = atomicAdd(&cursor[c_tbase[t] + d], 1);
    ssrc[pos] = s;
}

// ---------------- aggregate-first for ts->compact: aggx[d] = (sum_e ex*x[s_e]) / den ----
// compact dst order: vital 0..999, diag 1000..20999, med 21000..25999, proc 26000..33999
__global__ __launch_bounds__(256) void aggx_k(const float* __restrict__ attnT,
                                              const float* __restrict__ attnC,
                                              const float* __restrict__ xts,   // ts rows of xin
                                              const int* __restrict__ rowptr,
                                              const int* __restrict__ ssrc,
                                              float* __restrict__ aggx)
{
    int w = blockIdx.x * 4 + (threadIdx.x >> 6);   // 0..33999 (grid 8500 exact)
    int lane = threadIdx.x & 63;
    int h = lane >> 4;
    int ch = (h << 6) | ((lane & 15) << 2);
    int q, dloc;
    if (w < 1000)       { q = 0; dloc = w; }
    else if (w < 21000) { q = 1; dloc = w - 1000; }
    else if (w < 26000) { q = 2; dloc = w - 21000; }
    else                { q = 3; dloc = w - 26000; }
    const int csr4[4]  = {0, 51000, 121000, 176000};   // CSR bases for t=0,2,4,6
    const int soff4[4] = {0, 4, 8, 12};
    int r0 = rowptr[csr4[q] + dloc], r1 = rowptr[csr4[q] + dloc + 1];
    float ed = attnC[(size_t)w * 8 + 4 + h];
    float m = -1e30f;
    for (int e = r0; e < r1; e++) {
        int s = ssrc[e];
        float es = attnT[(size_t)s * 32 + soff4[q] + h];
        m = fmaxf(m, lrelu(es + ed));
    }
    float den = 0.f, sx = 0.f, sy = 0.f, sz = 0.f, sw = 0.f;
    for (int e = r0; e < r1; e++) {
        int s = ssrc[e];
        float es = attnT[(size_t)s * 32 + soff4[q] + h];
        float ex = __expf(lrelu(es + ed) - m);
        den += ex;
        const float4 xv = *(const float4*)(xts + (size_t)s * 256 + ch);
        sx += ex * xv.x; sy += ex * xv.y; sz += ex * xv.z; sw += ex * xv.w;
    }
    float inv = 1.f / (den + 1e-16f);
    float4 o; o.x = sx * inv; o.y = sy * inv; o.z = sz * inv; o.w = sw * inv;
    *(float4*)(aggx + (size_t)w * 256 + ch) = o;
}

// ---------------- fused aggregation: all 4 compact->ts types, one wave per ts node ------
__global__ __launch_bounds__(256) void agg_ts(const float* __restrict__ attnT,
                                              const float* __restrict__ attnC,
                                              const float* __restrict__ hsc,   // compact-indexed
                                              const int* __restrict__ rowptr,
                                              const int* __restrict__ ssrc,
                                              const float* __restrict__ bconv_l,
                                              float* __restrict__ xout)
{
    int d = blockIdx.x * 4 + (threadIdx.x >> 6);   // grid 12500 exact
    int lane = threadIdx.x & 63;
    int h = lane >> 4;
    int ch = (h << 6) | ((lane & 15) << 2);
    const int co4[4]   = {0, 1000, 21000, 26000};       // compact row base per src type
    const int tb4[4]   = {1000, 71000, 126000, 184000}; // CSR bases (t=1,3,5,7)
    const int doff4[4] = {16, 20, 24, 28};
    const int bo4[4]   = {256, 768, 1280, 1792};
    float ax = 0.f, ay = 0.f, az = 0.f, aw = 0.f;
#pragma unroll
    for (int q = 0; q < 4; q++) {
        const float* b = bconv_l + bo4[q] + ch;
        ax += b[0]; ay += b[1]; az += b[2]; aw += b[3];
    }
#pragma unroll
    for (int q = 0; q < 4; q++) {
        int r0 = rowptr[tb4[q] + d], r1 = rowptr[tb4[q] + d + 1];
        float ed = attnT[(size_t)d * 32 + doff4[q] + h];
        float m = -1e30f;
        for (int e = r0; e < r1; e++) {
            int s = ssrc[e];
            float es = attnC[(size_t)(co4[q] + s) * 8 + h];
            m = fmaxf(m, lrelu(es + ed));
        }
        float den = 0.f, sx = 0.f, sy = 0.f, sz = 0.f, sw = 0.f;
        for (int e = r0; e < r1; e++) {
            int s = ssrc[e];
            float es = attnC[(size_t)(co4[q] + s) * 8 + h];
            float ex = __expf(lrelu(es + ed) - m);
            den += ex;
            const float4 hv = *(const float4*)(hsc + (size_t)(co4[q] + s) * 256 + ch);
            sx += ex * hv.x; sy += ex * hv.y; sz += ex * hv.z; sw += ex * hv.w;
        }
        float inv = 1.f / (den + 1e-16f);
        ax += sx * inv; ay += sy * inv; az += sz * inv; aw += sw * inv;
    }
    float4 o;
    o.x = fmaxf(ax, 0.f); o.y = fmaxf(ay, 0.f);
    o.z = fmaxf(az, 0.f); o.w = fmaxf(aw, 0.f);
    *(float4*)(xout + (size_t)d * 256 + ch) = o;
}

// ---------------- pooling + head ----------------
__global__ __launch_bounds__(256) void colsum_ts(const float* __restrict__ x,
                                                 float* __restrict__ gsum)
{
    int c = threadIdx.x;
    float s = 0.f;
    for (int r = blockIdx.x; r < 50000; r += gridDim.x) s += x[(size_t)r * 256 + c];
    atomAddF(gsum + c, s);
}

__global__ __launch_bounds__(128) void head_k(const float* __restrict__ gsum,
                                              const float* __restrict__ Wc1,
                                              const float* __restrict__ bc1,
                                              const float* __restrict__ Wc2,
                                              const float* __restrict__ bc2,
                                              float* __restrict__ out)
{
    __shared__ float g[256];
    __shared__ float red[128];
    int t = threadIdx.x;
    g[t] = gsum[t] * (1.f / 50000.f);
    g[t + 128] = gsum[t + 128] * (1.f / 50000.f);
    __syncthreads();
    float acc = bc1[t];
    for (int k = 0; k < 256; k++) acc += g[k] * Wc1[k * 128 + t];
    red[t] = fmaxf(acc, 0.f) * Wc2[t];
    __syncthreads();
    for (int sft = 64; sft > 0; sft >>= 1) {
        if (t < sft) red[t] += red[t + sft];
        __syncthreads();
    }
    if (t == 0) out[0] = red[0] + bc2[0];
}

extern "C" void kernel_launch(void* const* d_in, const int* in_sizes, int n_in,
                              void* d_out, int out_size, void* d_ws, size_t ws_size,
                              hipStream_t stream)
{
    const float* ts_x   = (const float*)d_in[0];
    const float* emb[4] = {(const float*)d_in[1], (const float*)d_in[2],
                           (const float*)d_in[3], (const float*)d_in[4]};
    const float* Wp_ts  = (const float*)d_in[5];
    const float* bp_ts  = (const float*)d_in[6];
    const float* Wp_c   = (const float*)d_in[7];
    const float* bp_c   = (const float*)d_in[8];
    const float* Wsrc   = (const float*)d_in[9];
    const float* asrc   = (const float*)d_in[11];
    const float* Wdst   = (const float*)d_in[10];
    const float* adst   = (const float*)d_in[12];
    const float* bconv  = (const float*)d_in[13];
    const float* Wc1    = (const float*)d_in[14];
    const float* bc1    = (const float*)d_in[15];
    const float* Wc2    = (const float*)d_in[16];
    const float* bc2    = (const float*)d_in[17];
    EI8 ei;
    for (int t = 0; t < 8; t++) ei.p[t] = (const int*)d_in[18 + t];

    // workspace layout (floats)
    float* x0    = (float*)d_ws;           // 21,504,000
    float* x1    = x0    + 21504000;       // 21,504,000 (ts region doubles as aggx early in L1)
    float* hsc   = x1    + 21504000;       // 34000*256 = 8,704,000
    float* attnT = hsc   + 8704000;        // 50000*32 = 1,600,000
    float* attnC = attnT + 1600000;        // 34000*8  = 272,000
    float* weff  = attnC + 272000;         // 81,920
    float* gsum  = weff  + 81920;          // 256
    int* rowptr  = (int*)(gsum + 256);     // NDST+1
    int* bsum    = rowptr + 234004;
    int* ssrc    = bsum + 256;             // 800,000
    int* cursor  = (int*)hsc;              // alias: CSR build finishes before hsc is used
    float* aggx  = x1;                     // alias ts region of x1 (overwritten later by agg_ts)

    // ---- CSR build ----
    hipMemsetAsync(cursor, 0, NDST * sizeof(int), stream);
    count_k<<<3125, 256, 0, stream>>>(ei, cursor);
    scanA<<<229, 256, 0, stream>>>(cursor, rowptr, bsum);
    scanB<<<1, 256, 0, stream>>>(bsum, 229);
    scanC<<<229, 256, 0, stream>>>(rowptr, bsum, cursor);
    place_k<<<3125, 256, 0, stream>>>(ei, cursor, ssrc);

    fill_weff<<<320, 256, 0, stream>>>(Wsrc, Wdst, asrc, adst, weff);

    static const int Nd4[4]    = {1000, 20000, 5000, 8000};
    static const int co4[4]    = {0, 1000, 21000, 26000};
    static const int dbase4[4] = {50000, 51000, 71000, 76000};
    static const int tsrc[4]   = {1, 3, 5, 7};   // compact->ts types
    static const int tdst[4]   = {0, 2, 4, 6};   // ts->compact types

    // ---- input projections ----
    {
        GBatch b = {};
        b.j[0] = {ts_x, Wp_ts, x0, bp_ts, 50000, 64, 0, 0};
        gemm128<<<dim3(391, 2, 1), 256, 0, stream>>>(b);
    }
    {
        GBatch b = {};
        for (int q = 0; q < 4; q++)
            b.j[q] = {emb[q], Wp_c + q * 32768, x0 + (size_t)dbase4[q] * 256,
                      bp_c + q * 256, Nd4[q], 128, 0, 0};
        gemm128<<<dim3(157, 2, 4), 256, 0, stream>>>(b);
    }

    // ---- layer 1 ----
    attnproj<<<329, 256, 0, stream>>>(x0, weff, attnT, attnC);
    aggx_k<<<8500, 256, 0, stream>>>(attnT, attnC, x0, rowptr, ssrc, aggx);
    {
        GBatch b = {};
        for (int q = 0; q < 4; q++) {   // compact-source hs -> hsc (compact-indexed)
            b.j[q] = {x0 + (size_t)dbase4[q] * 256, Wsrc + (size_t)(0 * 8 + tsrc[q]) * 65536,
                      hsc + (size_t)co4[q] * 256, nullptr, Nd4[q], 256, 0, 0};
        }
        for (int q = 0; q < 4; q++) {   // aggx @ Ws + bias, relu -> x1 compact rows
            b.j[4 + q] = {aggx + (size_t)co4[q] * 256, Wsrc + (size_t)(0 * 8 + tdst[q]) * 65536,
                          x1 + (size_t)dbase4[q] * 256, bconv + tdst[q] * 256, Nd4[q], 256, 1, 0};
        }
        gemm128<<<dim3(157, 2, 8), 256, 0, stream>>>(b);
    }
    agg_ts<<<12500, 256, 0, stream>>>(attnT, attnC, hsc, rowptr, ssrc, bconv, x1);

    // ---- layer 2 (ts outputs only; compact outputs are dead) ----
    attnproj<<<329, 256, 0, stream>>>(x1, weff + 40960, attnT, attnC);
    {
        GBatch b = {};
        for (int q = 0; q < 4; q++)
            b.j[q] = {x1 + (size_t)dbase4[q] * 256, Wsrc + (size_t)(1 * 8 + tsrc[q]) * 65536,
                      hsc + (size_t)co4[q] * 256, nullptr, Nd4[q], 256, 0, 0};
        gemm128<<<dim3(157, 2, 4), 256, 0, stream>>>(b);
    }
    agg_ts<<<12500, 256, 0, stream>>>(attnT, attnC, hsc, rowptr, ssrc, bconv + 2048, x0);

    // ---- pooling + head ----
    hipMemsetAsync(gsum, 0, 256 * sizeof(float), stream);
    colsum_ts<<<256, 256, 0, stream>>>(x0, gsum);
    head_k<<<1, 128, 0, stream>>>(gsum, Wc1, bc1, Wc2, bc2, (float*)d_out);
}

// Round 4
// 796.073 us; speedup vs baseline: 9.8710x; 1.2174x over previous
//
#include <hip/hip_runtime.h>

#define E_N 100000
#define NTOT 84000
#define NDST 234000   // concatenated per-type dst index space

typedef __attribute__((ext_vector_type(8))) short bfrag8;
typedef __attribute__((ext_vector_type(4))) float accf4;

__device__ __forceinline__ void atomAddF(float* p, float v) {
    unsafeAtomicAdd(p, v);
}

__device__ __forceinline__ float lrelu(float v) { return v >= 0.f ? v : 0.2f * v; }

// fp32 -> bf16 round-to-nearest-even, and back
__device__ __forceinline__ unsigned short f2bf(float f) {
    unsigned u = __float_as_uint(f);
    return (unsigned short)((u + 0x7FFFu + ((u >> 16) & 1u)) >> 16);
}
__device__ __forceinline__ float bf2f(unsigned short h) {
    return __uint_as_float(((unsigned)h) << 16);
}

// CSR dst-space bases per edge type t
__constant__ int c_tbase[8] = {0, 1000, 51000, 71000, 121000, 126000, 176000, 184000};

struct EI8 { const int* p[8]; };

// ---------------- weight pre-split: W[K][256] fp32 -> BThi/BTlo[256][K] bf16 ----------
struct BTJob { const float* W; unsigned short* hi; unsigned short* lo; int K; int kshift; };
struct BTBatch { BTJob j[17]; };

__global__ __launch_bounds__(256) void makeBT(BTBatch b)
{
    BTJob jb = b.j[blockIdx.z];
    int idx = blockIdx.x * 256 + threadIdx.x;   // n*K + k
    if (idx >= (jb.K << 8)) return;
    int n = idx >> jb.kshift;
    int k = idx & (jb.K - 1);
    float w = jb.W[(size_t)k * 256 + n];
    unsigned short h = f2bf(w);
    jb.hi[idx] = h;
    jb.lo[idx] = f2bf(w - bf2f(h));
}

// ---------------- MFMA split-bf16 GEMM: C[M x 256] = A[M x K] @ B[K x 256] ------------
// 128x128 tile (grid.y=2), 4 waves in 2x2 quadrants, each 64x64 (4x4 MFMA 16x16x32 tiles).
// A fp32 split to hi/lo bf16 at staging; B pre-split panels, transposed [n][k].
// acc += Ahi*B1 + Alo*B1 + Ahi*B2   (missing Alo*B2 ~ 2^-16 relative)
struct MJob { const float* A; const unsigned short* BThi; const unsigned short* BTlo;
              float* C; const float* bias; int M; int K; int relu; };
struct MBatch { MJob j[8]; };

__global__ __launch_bounds__(256, 2) void gemm_mfma(MBatch batch)
{
    const MJob jb = batch.j[blockIdx.z];
    const int bm = blockIdx.x * 128;
    if (bm >= jb.M) return;
    const int bn = blockIdx.y * 128;
    const int M = jb.M, K = jb.K;

    __shared__ unsigned short Ah[128 * 40];
    __shared__ unsigned short Al[128 * 40];
    __shared__ unsigned short B1[128 * 40];
    __shared__ unsigned short B2[128 * 40];

    const int tid  = threadIdx.x;
    const int wv   = tid >> 6;
    const int lane = tid & 63;
    const int qr = wv >> 1, qc = wv & 1;
    const int lm = lane & 15;
    const int lq = lane >> 4;

    accf4 acc[4][4] = {};   // [mt][nt]

    for (int k0 = 0; k0 < K; k0 += 32) {
        // ---- stage A: 128 rows x 32 fp32, split hi/lo ----
#pragma unroll
        for (int it = 0; it < 4; ++it) {
            int slot = it * 256 + tid;       // 0..1023
            int m  = slot >> 3;              // 0..127
            int kq = (slot & 7) << 2;        // 0,4,...,28
            float4 v = make_float4(0.f, 0.f, 0.f, 0.f);
            if (bm + m < M) v = *(const float4*)(jb.A + (size_t)(bm + m) * K + k0 + kq);
            int o = m * 40 + kq;
            unsigned short h0 = f2bf(v.x), h1 = f2bf(v.y), h2 = f2bf(v.z), h3 = f2bf(v.w);
            Ah[o + 0] = h0; Ah[o + 1] = h1; Ah[o + 2] = h2; Ah[o + 3] = h3;
            Al[o + 0] = f2bf(v.x - bf2f(h0));
            Al[o + 1] = f2bf(v.y - bf2f(h1));
            Al[o + 2] = f2bf(v.z - bf2f(h2));
            Al[o + 3] = f2bf(v.w - bf2f(h3));
        }
        // ---- stage B: two parts, 128 n-rows x 32 k (bf16, transposed panels) ----
#pragma unroll
        for (int it = 0; it < 2; ++it) {
            int slot = it * 256 + tid;       // 0..511
            int n  = slot >> 2;              // 0..127
            int kq = (slot & 3) << 3;        // 0,8,16,24
            size_t go = (size_t)(bn + n) * K + k0 + kq;
            *(uint4*)&B1[n * 40 + kq] = *(const uint4*)(jb.BThi + go);
            *(uint4*)&B2[n * 40 + kq] = *(const uint4*)(jb.BTlo + go);
        }
        __syncthreads();

        bfrag8 ah[4], al[4], b1[4], b2[4];
#pragma unroll
        for (int t = 0; t < 4; ++t) {
            int am  = qr * 64 + t * 16 + lm;
            int bnn = qc * 64 + t * 16 + lm;
            ah[t] = *(const bfrag8*)&Ah[am * 40 + lq * 8];
            al[t] = *(const bfrag8*)&Al[am * 40 + lq * 8];
            b1[t] = *(const bfrag8*)&B1[bnn * 40 + lq * 8];
            b2[t] = *(const bfrag8*)&B2[bnn * 40 + lq * 8];
        }
#pragma unroll
        for (int mt = 0; mt < 4; ++mt)
#pragma unroll
            for (int nt = 0; nt < 4; ++nt) {
                acc[mt][nt] = __builtin_amdgcn_mfma_f32_16x16x32_bf16(ah[mt], b1[nt], acc[mt][nt], 0, 0, 0);
                acc[mt][nt] = __builtin_amdgcn_mfma_f32_16x16x32_bf16(al[mt], b1[nt], acc[mt][nt], 0, 0, 0);
                acc[mt][nt] = __builtin_amdgcn_mfma_f32_16x16x32_bf16(ah[mt], b2[nt], acc[mt][nt], 0, 0, 0);
            }
        __syncthreads();
    }

    // ---- epilogue: C/D layout col=lane&15, row=(lane>>4)*4+r ----
#pragma unroll
    for (int nt = 0; nt < 4; ++nt) {
        int col = bn + qc * 64 + nt * 16 + lm;
        float bv = jb.bias ? jb.bias[col] : 0.f;
#pragma unroll
        for (int mt = 0; mt < 4; ++mt) {
            int row0 = bm + qr * 64 + mt * 16 + lq * 4;
#pragma unroll
            for (int r = 0; r < 4; ++r) {
                int row = row0 + r;
                if (row < M) {
                    float o = acc[mt][nt][r] + bv;
                    if (jb.relu) o = fmaxf(o, 0.f);
                    jb.C[(size_t)row * 256 + col] = o;
                }
            }
        }
    }
}

// ---------------- effective attention-projection matrices ----------------
__global__ __launch_bounds__(256) void fill_weff(const float* __restrict__ Wsrc,
                                                 const float* __restrict__ Wdst,
                                                 const float* __restrict__ asrc,
                                                 const float* __restrict__ adst,
                                                 float* __restrict__ weff)
{
    int idx = blockIdx.x * 256 + threadIdx.x;
    if (idx >= 81920) return;
    int col = idx & 31;
    int k   = (idx >> 5) & 255;
    int lnt = idx >> 13;
    int nt  = lnt % 5;
    int l   = lnt / 5;
    bool is_src; int t, h;
    if (nt == 0) {
        if (col < 16) { is_src = true;  t = (col >> 2) * 2;            h = col & 3; }
        else          { is_src = false; t = ((col - 16) >> 2) * 2 + 1; h = col & 3; }
    } else {
        if (col < 4)      { is_src = true;  t = 2 * nt - 1; h = col; }
        else if (col < 8) { is_src = false; t = 2 * nt - 2; h = col - 4; }
        else { weff[idx] = 0.f; return; }
    }
    const float* W = (is_src ? Wsrc : Wdst) + ((size_t)((l * 8 + t) * 256 + k)) * 256 + h * 64;
    const float* a = (is_src ? asrc : adst) + ((size_t)((l * 8 + t) * 4 + h)) * 64;
    float val = 0.f;
    for (int c = 0; c < 64; c++) val += W[c] * a[c];
    weff[idx] = val;
}

// ---------------- attn projections ----------------
template<int NO>
__device__ __forceinline__ void attnproj_body(const float* __restrict__ xrow,
                                              const float* __restrict__ W,
                                              float* __restrict__ out)
{
    float acc[NO];
#pragma unroll
    for (int j = 0; j < NO; j++) acc[j] = 0.f;
    for (int k = 0; k < 256; k += 4) {
        const float4 xv = *(const float4*)(xrow + k);
#pragma unroll
        for (int j = 0; j < NO; j++) {
            acc[j] += xv.x * W[(k + 0) * 32 + j] + xv.y * W[(k + 1) * 32 + j]
                    + xv.z * W[(k + 2) * 32 + j] + xv.w * W[(k + 3) * 32 + j];
        }
    }
#pragma unroll
    for (int j = 0; j < NO; j++) out[j] = acc[j];
}

__global__ __launch_bounds__(256) void attnproj(const float* __restrict__ x,
                                                const float* __restrict__ weff_l,
                                                float* __restrict__ attnT,
                                                float* __restrict__ attnC)
{
    int n = blockIdx.x * 256 + threadIdx.x;
    if (n >= NTOT) return;
    if (n < 50000) {
        attnproj_body<32>(x + (size_t)n * 256, weff_l, attnT + (size_t)n * 32);
    } else {
        int nt = (n < 51000) ? 1 : (n < 71000) ? 2 : (n < 76000) ? 3 : 4;
        attnproj_body<8>(x + (size_t)n * 256, weff_l + nt * 8192, attnC + (size_t)(n - 50000) * 8);
    }
}

// ---------------- CSR build ----------------
__global__ __launch_bounds__(256) void count_k(EI8 ei, int* __restrict__ cnt)
{
    int g = blockIdx.x * 256 + threadIdx.x;
    if (g >= 8 * E_N) return;
    int t = g / E_N;
    int i = g - t * E_N;
    int d = ei.p[t][E_N + i];
    atomicAdd(&cnt[c_tbase[t] + d], 1);
}

__global__ __launch_bounds__(256) void scanA(const int* __restrict__ cnt,
                                             int* __restrict__ rowptr,
                                             int* __restrict__ bsum)
{
    __shared__ int sd[256];
    int b = blockIdx.x, t = threadIdx.x;
    int base = b * 1024 + t * 4;
    int v0 = 0, v1 = 0, v2 = 0, v3 = 0;
    if (base + 0 < NDST) v0 = cnt[base + 0];
    if (base + 1 < NDST) v1 = cnt[base + 1];
    if (base + 2 < NDST) v2 = cnt[base + 2];
    if (base + 3 < NDST) v3 = cnt[base + 3];
    int s = v0 + v1 + v2 + v3;
    sd[t] = s;
    __syncthreads();
    for (int off = 1; off < 256; off <<= 1) {
        int x = 0;
        if (t >= off) x = sd[t - off];
        __syncthreads();
        if (t >= off) sd[t] += x;
        __syncthreads();
    }
    int run = sd[t] - s;
    if (t == 255) bsum[b] = sd[255];
    if (base + 0 < NDST) rowptr[base + 0] = run;          run += v0;
    if (base + 1 < NDST) rowptr[base + 1] = run;          run += v1;
    if (base + 2 < NDST) rowptr[base + 2] = run;          run += v2;
    if (base + 3 < NDST) rowptr[base + 3] = run;
}

__global__ __launch_bounds__(256) void scanB(int* __restrict__ bsum, int nb)
{
    __shared__ int sd[256];
    int t = threadIdx.x;
    int v = (t < nb) ? bsum[t] : 0;
    sd[t] = v;
    __syncthreads();
    for (int off = 1; off < 256; off <<= 1) {
        int x = 0;
        if (t >= off) x = sd[t - off];
        __syncthreads();
        if (t >= off) sd[t] += x;
        __syncthreads();
    }
    if (t < nb) bsum[t] = sd[t] - v;
}

__global__ __launch_bounds__(256) void scanC(int* __restrict__ rowptr,
                                             const int* __restrict__ bsum,
                                             int* __restrict__ cursor)
{
    int b = blockIdx.x, t = threadIdx.x;
    int off = bsum[b];
    int base = b * 1024 + t * 4;
#pragma unroll
    for (int j = 0; j < 4; j++) {
        int i = base + j;
        if (i < NDST) {
            int r = rowptr[i] + off;
            rowptr[i] = r;
            cursor[i] = r;
        }
    }
    if (b == 0 && t == 0) rowptr[NDST] = 8 * E_N;
}

__global__ __launch_bounds__(256) void place_k(EI8 ei, int* __restrict__ cursor,
                                               int* __restrict__ ssrc)
{
    int g = blockIdx.x * 256 + threadIdx.x;
    if (g >= 8 * E_N) return;
    int t = g / E_N;
    int i = g - t * E_N;
    int d = ei.p[t][E_N + i];
    int s = ei.p[t][i];
    int pos = atomicAdd(&cursor[c_tbase[t] + d], 1);
    ssrc[pos] = s;
}

// ---------------- aggregate-first for ts->compact (single-pass, no max shift) ---------
__global__ __launch_bounds__(256) void aggx_k(const float* __restrict__ attnT,
                                              const float* __restrict__ attnC,
                                              const float* __restrict__ xts,
                                              const int* __restrict__ rowptr,
                                              const int* __restrict__ ssrc,
                                              float* __restrict__ aggx)
{
    int w = blockIdx.x * 4 + (threadIdx.x >> 6);   // 0..33999 (grid 8500)
    int lane = threadIdx.x & 63;
    int h = lane >> 4;
    int ch = (h << 6) | ((lane & 15) << 2);
    int q, dloc;
    if (w < 1000)       { q = 0; dloc = w; }
    else if (w < 21000) { q = 1; dloc = w - 1000; }
    else if (w < 26000) { q = 2; dloc = w - 21000; }
    else                { q = 3; dloc = w - 26000; }
    const int csr4[4]  = {0, 51000, 121000, 176000};   // CSR bases for t=0,2,4,6
    const int soff4[4] = {0, 4, 8, 12};
    int r0 = rowptr[csr4[q] + dloc], r1 = rowptr[csr4[q] + dloc + 1];
    float ed = attnC[(size_t)w * 8 + 4 + h];
    float den = 0.f, sx = 0.f, sy = 0.f, sz = 0.f, sw = 0.f;
    for (int e = r0; e < r1; e++) {
        int s = ssrc[e];
        float es = attnT[(size_t)s * 32 + soff4[q] + h];
        float ex = __expf(lrelu(es + ed));   // logits are O(1): no max-shift needed
        den += ex;
        const float4 xv = *(const float4*)(xts + (size_t)s * 256 + ch);
        sx += ex * xv.x; sy += ex * xv.y; sz += ex * xv.z; sw += ex * xv.w;
    }
    float inv = 1.f / (den + 1e-16f);
    float4 o; o.x = sx * inv; o.y = sy * inv; o.z = sz * inv; o.w = sw * inv;
    *(float4*)(aggx + (size_t)w * 256 + ch) = o;
}

// ---------------- fused aggregation: 4 compact->ts types (single-pass) ----------------
__global__ __launch_bounds__(256) void agg_ts(const float* __restrict__ attnT,
                                              const float* __restrict__ attnC,
                                              const float* __restrict__ hsc,
                                              const int* __restrict__ rowptr,
                                              const int* __restrict__ ssrc,
                                              const float* __restrict__ bconv_l,
                                              float* __restrict__ xout)
{
    int d = blockIdx.x * 4 + (threadIdx.x >> 6);   // grid 12500
    int lane = threadIdx.x & 63;
    int h = lane >> 4;
    int ch = (h << 6) | ((lane & 15) << 2);
    const int co4[4]   = {0, 1000, 21000, 26000};
    const int tb4[4]   = {1000, 71000, 126000, 184000};
    const int doff4[4] = {16, 20, 24, 28};
    const int bo4[4]   = {256, 768, 1280, 1792};
    float ax = 0.f, ay = 0.f, az = 0.f, aw = 0.f;
#pragma unroll
    for (int q = 0; q < 4; q++) {
        const float* b = bconv_l + bo4[q] + ch;
        ax += b[0]; ay += b[1]; az += b[2]; aw += b[3];
    }
#pragma unroll
    for (int q = 0; q < 4; q++) {
        int r0 = rowptr[tb4[q] + d], r1 = rowptr[tb4[q] + d + 1];
        float ed = attnT[(size_t)d * 32 + doff4[q] + h];
        float den = 0.f, sx = 0.f, sy = 0.f, sz = 0.f, sw = 0.f;
        for (int e = r0; e < r1; e++) {
            int s = ssrc[e];
            float es = attnC[(size_t)(co4[q] + s) * 8 + h];
            float ex = __expf(lrelu(es + ed));
            den += ex;
            const float4 hv = *(const float4*)(hsc + (size_t)(co4[q] + s) * 256 + ch);
            sx += ex * hv.x; sy += ex * hv.y; sz += ex * hv.z; sw += ex * hv.w;
        }
        float inv = 1.f / (den + 1e-16f);
        ax += sx * inv; ay += sy * inv; az += sz * inv; aw += sw * inv;
    }
    float4 o;
    o.x = fmaxf(ax, 0.f); o.y = fmaxf(ay, 0.f);
    o.z = fmaxf(az, 0.f); o.w = fmaxf(aw, 0.f);
    *(float4*)(xout + (size_t)d * 256 + ch) = o;
}

// ---------------- pooling + head ----------------
__global__ __launch_bounds__(256) void colsum_ts(const float* __restrict__ x,
                                                 float* __restrict__ gsum)
{
    int c = threadIdx.x;
    float s = 0.f;
    for (int r = blockIdx.x; r < 50000; r += gridDim.x) s += x[(size_t)r * 256 + c];
    atomAddF(gsum + c, s);
}

__global__ __launch_bounds__(128) void head_k(const float* __restrict__ gsum,
                                              const float* __restrict__ Wc1,
                                              const float* __restrict__ bc1,
                                              const float* __restrict__ Wc2,
                                              const float* __restrict__ bc2,
                                              float* __restrict__ out)
{
    __shared__ float g[256];
    __shared__ float red[128];
    int t = threadIdx.x;
    g[t] = gsum[t] * (1.f / 50000.f);
    g[t + 128] = gsum[t + 128] * (1.f / 50000.f);
    __syncthreads();
    float acc = bc1[t];
    for (int k = 0; k < 256; k++) acc += g[k] * Wc1[k * 128 + t];
    red[t] = fmaxf(acc, 0.f) * Wc2[t];
    __syncthreads();
    for (int sft = 64; sft > 0; sft >>= 1) {
        if (t < sft) red[t] += red[t + sft];
        __syncthreads();
    }
    if (t == 0) out[0] = red[0] + bc2[0];
}

extern "C" void kernel_launch(void* const* d_in, const int* in_sizes, int n_in,
                              void* d_out, int out_size, void* d_ws, size_t ws_size,
                              hipStream_t stream)
{
    const float* ts_x   = (const float*)d_in[0];
    const float* emb[4] = {(const float*)d_in[1], (const float*)d_in[2],
                           (const float*)d_in[3], (const float*)d_in[4]};
    const float* Wp_ts  = (const float*)d_in[5];
    const float* bp_ts  = (const float*)d_in[6];
    const float* Wp_c   = (const float*)d_in[7];
    const float* bp_c   = (const float*)d_in[8];
    const float* Wsrc   = (const float*)d_in[9];
    const float* Wdst   = (const float*)d_in[10];
    const float* asrc   = (const float*)d_in[11];
    const float* adst   = (const float*)d_in[12];
    const float* bconv  = (const float*)d_in[13];
    const float* Wc1    = (const float*)d_in[14];
    const float* bc1    = (const float*)d_in[15];
    const float* Wc2    = (const float*)d_in[16];
    const float* bc2    = (const float*)d_in[17];
    EI8 ei;
    for (int t = 0; t < 8; t++) ei.p[t] = (const int*)d_in[18 + t];

    // workspace layout (floats)
    float* x0    = (float*)d_ws;           // 21,504,000
    float* x1    = x0    + 21504000;       // 21,504,000 (ts region doubles as aggx in L1)
    float* hsc   = x1    + 21504000;       // 34000*256 = 8,704,000
    float* attnT = hsc   + 8704000;        // 1,600,000
    float* attnC = attnT + 1600000;        // 272,000
    float* weff  = attnC + 272000;         // 81,920
    float* gsum  = weff  + 81920;          // 256
    int* rowptr  = (int*)(gsum + 256);     // NDST+1
    int* bsum    = rowptr + 234004;        // 256
    int* ssrc    = bsum + 256;             // 800,000
    unsigned short* btp = (unsigned short*)(ssrc + 800000);  // bf16 panels, ~1.87M elems
    int* cursor  = (int*)hsc;              // alias: CSR build finishes before hsc is used
    float* aggx  = x1;                     // alias ts region of x1

    // panel offsets (bf16 elems): [p_ts | p_c x4 | L1 t0..7 | L2 t1,3,5,7], each x2 (hi,lo)
    // p_ts: 256*64, p_c: 256*128, Wsrc: 256*256
    unsigned short* bt_ts_h = btp;                      // 16384
    unsigned short* bt_ts_l = bt_ts_h + 16384;
    unsigned short* bt_c_h[4], *bt_c_l[4];
    {
        unsigned short* p = bt_ts_l + 16384;
        for (int q = 0; q < 4; q++) { bt_c_h[q] = p; p += 32768; bt_c_l[q] = p; p += 32768; }
        // Wsrc panels
    }
    unsigned short* bt_w = bt_ts_l + 16384 + 8 * 32768;
    auto wpan_h = [&](int l, int t) { return bt_w + (size_t)((l == 0 ? t : 8 + t / 2) * 2) * 65536; };
    auto wpan_l = [&](int l, int t) { return wpan_h(l, t) + 65536; };

    // ---- CSR build ----
    hipMemsetAsync(cursor, 0, NDST * sizeof(int), stream);
    count_k<<<3125, 256, 0, stream>>>(ei, cursor);
    scanA<<<229, 256, 0, stream>>>(cursor, rowptr, bsum);
    scanB<<<1, 256, 0, stream>>>(bsum, 229);
    scanC<<<229, 256, 0, stream>>>(rowptr, bsum, cursor);
    place_k<<<3125, 256, 0, stream>>>(ei, cursor, ssrc);

    // ---- weight pre-split (17 panels, one launch) ----
    {
        BTBatch b = {};
        int zi = 0;
        b.j[zi++] = {Wp_ts, bt_ts_h, bt_ts_l, 64, 6};
        for (int q = 0; q < 4; q++)
            b.j[zi++] = {Wp_c + q * 32768, bt_c_h[q], bt_c_l[q], 128, 7};
        for (int t = 0; t < 8; t++)
            b.j[zi++] = {Wsrc + (size_t)(0 * 8 + t) * 65536, wpan_h(0, t), wpan_l(0, t), 256, 8};
        for (int t = 1; t < 8; t += 2)
            b.j[zi++] = {Wsrc + (size_t)(1 * 8 + t) * 65536, wpan_h(1, t), wpan_l(1, t), 256, 8};
        makeBT<<<dim3(256, 1, 17), 256, 0, stream>>>(b);
    }

    fill_weff<<<320, 256, 0, stream>>>(Wsrc, Wdst, asrc, adst, weff);

    static const int Nd4[4]    = {1000, 20000, 5000, 8000};
    static const int co4[4]    = {0, 1000, 21000, 26000};
    static const int dbase4[4] = {50000, 51000, 71000, 76000};
    static const int tsrc[4]   = {1, 3, 5, 7};
    static const int tdst[4]   = {0, 2, 4, 6};

    // ---- input projections ----
    {
        MBatch b = {};
        b.j[0] = {ts_x, bt_ts_h, bt_ts_l, x0, bp_ts, 50000, 64, 0};
        for (int q = 0; q < 4; q++)
            b.j[1 + q] = {emb[q], bt_c_h[q], bt_c_l[q], x0 + (size_t)dbase4[q] * 256,
                          bp_c + q * 256, Nd4[q], 128, 0};
        gemm_mfma<<<dim3(391, 2, 5), 256, 0, stream>>>(b);
    }

    // ---- layer 1 ----
    attnproj<<<329, 256, 0, stream>>>(x0, weff, attnT, attnC);
    aggx_k<<<8500, 256, 0, stream>>>(attnT, attnC, x0, rowptr, ssrc, aggx);
    {
        MBatch b = {};
        for (int q = 0; q < 4; q++)
            b.j[q] = {x0 + (size_t)dbase4[q] * 256, wpan_h(0, tsrc[q]), wpan_l(0, tsrc[q]),
                      hsc + (size_t)co4[q] * 256, nullptr, Nd4[q], 256, 0};
        for (int q = 0; q < 4; q++)
            b.j[4 + q] = {aggx + (size_t)co4[q] * 256, wpan_h(0, tdst[q]), wpan_l(0, tdst[q]),
                          x1 + (size_t)dbase4[q] * 256, bconv + tdst[q] * 256, Nd4[q], 256, 1};
        gemm_mfma<<<dim3(157, 2, 8), 256, 0, stream>>>(b);
    }
    agg_ts<<<12500, 256, 0, stream>>>(attnT, attnC, hsc, rowptr, ssrc, bconv, x1);

    // ---- layer 2 (ts outputs only) ----
    attnproj<<<329, 256, 0, stream>>>(x1, weff + 40960, attnT, attnC);
    {
        MBatch b = {};
        for (int q = 0; q < 4; q++)
            b.j[q] = {x1 + (size_t)dbase4[q] * 256, wpan_h(1, tsrc[q]), wpan_l(1, tsrc[q]),
                      hsc + (size_t)co4[q] * 256, nullptr, Nd4[q], 256, 0};
        gemm_mfma<<<dim3(157, 2, 4), 256, 0, stream>>>(b);
    }
    agg_ts<<<12500, 256, 0, stream>>>(attnT, attnC, hsc, rowptr, ssrc, bconv + 2048, x0);

    // ---- pooling + head ----
    hipMemsetAsync(gsum, 0, 256 * sizeof(float), stream);
    colsum_ts<<<256, 256, 0, stream>>>(x0, gsum);
    head_k<<<1, 128, 0, stream>>>(gsum, Wc1, bc1, Wc2, bc2, (float*)d_out);
}

// Round 5
// 756.734 us; speedup vs baseline: 10.3842x; 1.0520x over previous
//
#include <hip/hip_runtime.h>

#define E_N 100000
#define NTOT 84000
#define NDST 234000   // concatenated per-type dst index space

typedef __attribute__((ext_vector_type(8))) short bfrag8;
typedef __attribute__((ext_vector_type(4))) float accf4;

__device__ __forceinline__ void atomAddF(float* p, float v) {
    unsafeAtomicAdd(p, v);
}

__device__ __forceinline__ float lrelu(float v) { return v >= 0.f ? v : 0.2f * v; }

// fp32 -> bf16 round-to-nearest-even, and back
__device__ __forceinline__ unsigned short f2bf(float f) {
    unsigned u = __float_as_uint(f);
    return (unsigned short)((u + 0x7FFFu + ((u >> 16) & 1u)) >> 16);
}
__device__ __forceinline__ float bf2f(unsigned short h) {
    return __uint_as_float(((unsigned)h) << 16);
}

// CSR dst-space bases per edge type t
__constant__ int c_tbase[8] = {0, 1000, 51000, 71000, 121000, 126000, 176000, 184000};

struct EI8 { const int* p[8]; };

// ---------------- weight pre-split: W[K][256] fp32 -> BThi/BTlo[256][K] bf16 ----------
struct BTJob { const float* W; unsigned short* hi; unsigned short* lo; int K; int kshift; };
struct BTBatch { BTJob j[17]; };

__global__ __launch_bounds__(256) void makeBT(BTBatch b)
{
    BTJob jb = b.j[blockIdx.z];
    int idx = blockIdx.x * 256 + threadIdx.x;   // n*K + k
    if (idx >= (jb.K << 8)) return;
    int n = idx >> jb.kshift;
    int k = idx & (jb.K - 1);
    float w = jb.W[(size_t)k * 256 + n];
    unsigned short h = f2bf(w);
    jb.hi[idx] = h;
    jb.lo[idx] = f2bf(w - bf2f(h));
}

// ---------------- MFMA split-bf16 GEMM: C[M x 256] = A[M x K] @ B[K x 256] ------------
// 128x128 tile (grid.y=2), 4 waves 2x2 quadrants, 4x4 MFMA 16x16x32 tiles each.
// acc += Ahi*B1 + Alo*B1 + Ahi*B2
struct MJob { const float* A; const unsigned short* BThi; const unsigned short* BTlo;
              float* C; unsigned short* Cbf; const float* bias; int M; int K; int relu; };
struct MBatch { MJob j[8]; };

__global__ __launch_bounds__(256, 2) void gemm_mfma(MBatch batch)
{
    const MJob jb = batch.j[blockIdx.z];
    const int bm = blockIdx.x * 128;
    if (bm >= jb.M) return;
    const int bn = blockIdx.y * 128;
    const int M = jb.M, K = jb.K;

    __shared__ unsigned short Ah[128 * 40];
    __shared__ unsigned short Al[128 * 40];
    __shared__ unsigned short B1[128 * 40];
    __shared__ unsigned short B2[128 * 40];

    const int tid  = threadIdx.x;
    const int wv   = tid >> 6;
    const int lane = tid & 63;
    const int qr = wv >> 1, qc = wv & 1;
    const int lm = lane & 15;
    const int lq = lane >> 4;

    accf4 acc[4][4] = {};   // [mt][nt]

    for (int k0 = 0; k0 < K; k0 += 32) {
#pragma unroll
        for (int it = 0; it < 4; ++it) {
            int slot = it * 256 + tid;
            int m  = slot >> 3;
            int kq = (slot & 7) << 2;
            float4 v = make_float4(0.f, 0.f, 0.f, 0.f);
            if (bm + m < M) v = *(const float4*)(jb.A + (size_t)(bm + m) * K + k0 + kq);
            int o = m * 40 + kq;
            unsigned short h0 = f2bf(v.x), h1 = f2bf(v.y), h2 = f2bf(v.z), h3 = f2bf(v.w);
            Ah[o + 0] = h0; Ah[o + 1] = h1; Ah[o + 2] = h2; Ah[o + 3] = h3;
            Al[o + 0] = f2bf(v.x - bf2f(h0));
            Al[o + 1] = f2bf(v.y - bf2f(h1));
            Al[o + 2] = f2bf(v.z - bf2f(h2));
            Al[o + 3] = f2bf(v.w - bf2f(h3));
        }
#pragma unroll
        for (int it = 0; it < 2; ++it) {
            int slot = it * 256 + tid;
            int n  = slot >> 2;
            int kq = (slot & 3) << 3;
            size_t go = (size_t)(bn + n) * K + k0 + kq;
            *(uint4*)&B1[n * 40 + kq] = *(const uint4*)(jb.BThi + go);
            *(uint4*)&B2[n * 40 + kq] = *(const uint4*)(jb.BTlo + go);
        }
        __syncthreads();

        bfrag8 ah[4], al[4], b1[4], b2[4];
#pragma unroll
        for (int t = 0; t < 4; ++t) {
            int am  = qr * 64 + t * 16 + lm;
            int bnn = qc * 64 + t * 16 + lm;
            ah[t] = *(const bfrag8*)&Ah[am * 40 + lq * 8];
            al[t] = *(const bfrag8*)&Al[am * 40 + lq * 8];
            b1[t] = *(const bfrag8*)&B1[bnn * 40 + lq * 8];
            b2[t] = *(const bfrag8*)&B2[bnn * 40 + lq * 8];
        }
#pragma unroll
        for (int mt = 0; mt < 4; ++mt)
#pragma unroll
            for (int nt = 0; nt < 4; ++nt) {
                acc[mt][nt] = __builtin_amdgcn_mfma_f32_16x16x32_bf16(ah[mt], b1[nt], acc[mt][nt], 0, 0, 0);
                acc[mt][nt] = __builtin_amdgcn_mfma_f32_16x16x32_bf16(al[mt], b1[nt], acc[mt][nt], 0, 0, 0);
                acc[mt][nt] = __builtin_amdgcn_mfma_f32_16x16x32_bf16(ah[mt], b2[nt], acc[mt][nt], 0, 0, 0);
            }
        __syncthreads();
    }

    // ---- epilogue: C/D layout col=lane&15, row=(lane>>4)*4+r ----
#pragma unroll
    for (int nt = 0; nt < 4; ++nt) {
        int col = bn + qc * 64 + nt * 16 + lm;
        float bv = jb.bias ? jb.bias[col] : 0.f;
#pragma unroll
        for (int mt = 0; mt < 4; ++mt) {
            int row0 = bm + qr * 64 + mt * 16 + lq * 4;
#pragma unroll
            for (int r = 0; r < 4; ++r) {
                int row = row0 + r;
                if (row < M) {
                    float o = acc[mt][nt][r] + bv;
                    if (jb.relu) o = fmaxf(o, 0.f);
                    if (jb.C)   jb.C[(size_t)row * 256 + col] = o;
                    if (jb.Cbf) jb.Cbf[(size_t)row * 256 + col] = f2bf(o);
                }
            }
        }
    }
}

// ---------------- effective attention-projection matrices ----------------
__global__ __launch_bounds__(256) void fill_weff(const float* __restrict__ Wsrc,
                                                 const float* __restrict__ Wdst,
                                                 const float* __restrict__ asrc,
                                                 const float* __restrict__ adst,
                                                 float* __restrict__ weff)
{
    int idx = blockIdx.x * 256 + threadIdx.x;
    if (idx >= 81920) return;
    int col = idx & 31;
    int k   = (idx >> 5) & 255;
    int lnt = idx >> 13;
    int nt  = lnt % 5;
    int l   = lnt / 5;
    bool is_src; int t, h;
    if (nt == 0) {
        if (col < 16) { is_src = true;  t = (col >> 2) * 2;            h = col & 3; }
        else          { is_src = false; t = ((col - 16) >> 2) * 2 + 1; h = col & 3; }
    } else {
        if (col < 4)      { is_src = true;  t = 2 * nt - 1; h = col; }
        else if (col < 8) { is_src = false; t = 2 * nt - 2; h = col - 4; }
        else { weff[idx] = 0.f; return; }
    }
    const float* W = (is_src ? Wsrc : Wdst) + ((size_t)((l * 8 + t) * 256 + k)) * 256 + h * 64;
    const float* a = (is_src ? asrc : adst) + ((size_t)((l * 8 + t) * 4 + h)) * 64;
    float val = 0.f;
    for (int c = 0; c < 64; c++) val += W[c] * a[c];
    weff[idx] = val;
}

// ---------------- attn projections ----------------
template<int NO>
__device__ __forceinline__ void attnproj_body(const float* __restrict__ xrow,
                                              const float* __restrict__ W,
                                              float* __restrict__ out)
{
    float acc[NO];
#pragma unroll
    for (int j = 0; j < NO; j++) acc[j] = 0.f;
    for (int k = 0; k < 256; k += 4) {
        const float4 xv = *(const float4*)(xrow + k);
#pragma unroll
        for (int j = 0; j < NO; j++) {
            acc[j] += xv.x * W[(k + 0) * 32 + j] + xv.y * W[(k + 1) * 32 + j]
                    + xv.z * W[(k + 2) * 32 + j] + xv.w * W[(k + 3) * 32 + j];
        }
    }
#pragma unroll
    for (int j = 0; j < NO; j++) out[j] = acc[j];
}

__global__ __launch_bounds__(256) void attnproj(const float* __restrict__ x,
                                                const float* __restrict__ weff_l,
                                                float* __restrict__ attnT,
                                                float* __restrict__ attnC)
{
    int n = blockIdx.x * 256 + threadIdx.x;
    if (n >= NTOT) return;
    if (n < 50000) {
        attnproj_body<32>(x + (size_t)n * 256, weff_l, attnT + (size_t)n * 32);
    } else {
        int nt = (n < 51000) ? 1 : (n < 71000) ? 2 : (n < 76000) ? 3 : 4;
        attnproj_body<8>(x + (size_t)n * 256, weff_l + nt * 8192, attnC + (size_t)(n - 50000) * 8);
    }
}

// ---------------- CSR build ----------------
__global__ __launch_bounds__(256) void count_k(EI8 ei, int* __restrict__ cnt)
{
    int g = blockIdx.x * 256 + threadIdx.x;
    if (g >= 8 * E_N) return;
    int t = g / E_N;
    int i = g - t * E_N;
    int d = ei.p[t][E_N + i];
    atomicAdd(&cnt[c_tbase[t] + d], 1);
}

__global__ __launch_bounds__(256) void scanA(const int* __restrict__ cnt,
                                             int* __restrict__ rowptr,
                                             int* __restrict__ bsum)
{
    __shared__ int sd[256];
    int b = blockIdx.x, t = threadIdx.x;
    int base = b * 1024 + t * 4;
    int v0 = 0, v1 = 0, v2 = 0, v3 = 0;
    if (base + 0 < NDST) v0 = cnt[base + 0];
    if (base + 1 < NDST) v1 = cnt[base + 1];
    if (base + 2 < NDST) v2 = cnt[base + 2];
    if (base + 3 < NDST) v3 = cnt[base + 3];
    int s = v0 + v1 + v2 + v3;
    sd[t] = s;
    __syncthreads();
    for (int off = 1; off < 256; off <<= 1) {
        int x = 0;
        if (t >= off) x = sd[t - off];
        __syncthreads();
        if (t >= off) sd[t] += x;
        __syncthreads();
    }
    int run = sd[t] - s;
    if (t == 255) bsum[b] = sd[255];
    if (base + 0 < NDST) rowptr[base + 0] = run;          run += v0;
    if (base + 1 < NDST) rowptr[base + 1] = run;          run += v1;
    if (base + 2 < NDST) rowptr[base + 2] = run;          run += v2;
    if (base + 3 < NDST) rowptr[base + 3] = run;
}

__global__ __launch_bounds__(256) void scanB(int* __restrict__ bsum, int nb)
{
    __shared__ int sd[256];
    int t = threadIdx.x;
    int v = (t < nb) ? bsum[t] : 0;
    sd[t] = v;
    __syncthreads();
    for (int off = 1; off < 256; off <<= 1) {
        int x = 0;
        if (t >= off) x = sd[t - off];
        __syncthreads();
        if (t >= off) sd[t] += x;
        __syncthreads();
    }
    if (t < nb) bsum[t] = sd[t] - v;
}

__global__ __launch_bounds__(256) void scanC(int* __restrict__ rowptr,
                                             const int* __restrict__ bsum,
                                             int* __restrict__ cursor)
{
    int b = blockIdx.x, t = threadIdx.x;
    int off = bsum[b];
    int base = b * 1024 + t * 4;
#pragma unroll
    for (int j = 0; j < 4; j++) {
        int i = base + j;
        if (i < NDST) {
            int r = rowptr[i] + off;
            rowptr[i] = r;
            cursor[i] = r;
        }
    }
    if (b == 0 && t == 0) rowptr[NDST] = 8 * E_N;
}

__global__ __launch_bounds__(256) void place_k(EI8 ei, int* __restrict__ cursor,
                                               int* __restrict__ ssrc)
{
    int g = blockIdx.x * 256 + threadIdx.x;
    if (g >= 8 * E_N) return;
    int t = g / E_N;
    int i = g - t * E_N;
    int d = ei.p[t][E_N + i];
    int s = ei.p[t][i];
    int pos = atomicAdd(&cursor[c_tbase[t] + d], 1);
    ssrc[pos] = s;
}

// ---------------- aggregate-first ts->compact: bf16 gather, unroll-4 -----------------
__global__ __launch_bounds__(256) void aggx_k(const float* __restrict__ attnT,
                                              const float* __restrict__ attnC,
                                              const unsigned short* __restrict__ xtsbf,
                                              const int* __restrict__ rowptr,
                                              const int* __restrict__ ssrc,
                                              float* __restrict__ aggx)
{
    int w = blockIdx.x * 4 + (threadIdx.x >> 6);   // 0..33999 (grid 8500)
    int lane = threadIdx.x & 63;
    int h = lane >> 4;
    int ch = (h << 6) | ((lane & 15) << 2);
    int q, dloc;
    if (w < 1000)       { q = 0; dloc = w; }
    else if (w < 21000) { q = 1; dloc = w - 1000; }
    else if (w < 26000) { q = 2; dloc = w - 21000; }
    else                { q = 3; dloc = w - 26000; }
    const int csr4[4]  = {0, 51000, 121000, 176000};
    const int soff4[4] = {0, 4, 8, 12};
    int soff = soff4[q];
    int r0 = rowptr[csr4[q] + dloc], r1 = rowptr[csr4[q] + dloc + 1];
    float ed = attnC[(size_t)w * 8 + 4 + h];
    float den = 0.f, sx = 0.f, sy = 0.f, sz = 0.f, sw = 0.f;
    int e = r0;
    for (; e + 4 <= r1; e += 4) {
        int sA = ssrc[e], sB = ssrc[e + 1], sC = ssrc[e + 2], sD = ssrc[e + 3];
        float eA = attnT[(size_t)sA * 32 + soff + h];
        float eB = attnT[(size_t)sB * 32 + soff + h];
        float eC = attnT[(size_t)sC * 32 + soff + h];
        float eD = attnT[(size_t)sD * 32 + soff + h];
        ushort4 rA = *(const ushort4*)(xtsbf + (size_t)sA * 256 + ch);
        ushort4 rB = *(const ushort4*)(xtsbf + (size_t)sB * 256 + ch);
        ushort4 rC = *(const ushort4*)(xtsbf + (size_t)sC * 256 + ch);
        ushort4 rD = *(const ushort4*)(xtsbf + (size_t)sD * 256 + ch);
        float xA = __expf(lrelu(eA + ed));
        float xB = __expf(lrelu(eB + ed));
        float xC = __expf(lrelu(eC + ed));
        float xD = __expf(lrelu(eD + ed));
        den += (xA + xB) + (xC + xD);
        sx += xA * bf2f(rA.x) + xB * bf2f(rB.x) + xC * bf2f(rC.x) + xD * bf2f(rD.x);
        sy += xA * bf2f(rA.y) + xB * bf2f(rB.y) + xC * bf2f(rC.y) + xD * bf2f(rD.y);
        sz += xA * bf2f(rA.z) + xB * bf2f(rB.z) + xC * bf2f(rC.z) + xD * bf2f(rD.z);
        sw += xA * bf2f(rA.w) + xB * bf2f(rB.w) + xC * bf2f(rC.w) + xD * bf2f(rD.w);
    }
    for (; e < r1; e++) {
        int s = ssrc[e];
        float es = attnT[(size_t)s * 32 + soff + h];
        float ex = __expf(lrelu(es + ed));
        den += ex;
        ushort4 rv = *(const ushort4*)(xtsbf + (size_t)s * 256 + ch);
        sx += ex * bf2f(rv.x); sy += ex * bf2f(rv.y);
        sz += ex * bf2f(rv.z); sw += ex * bf2f(rv.w);
    }
    float inv = 1.f / (den + 1e-16f);
    float4 o; o.x = sx * inv; o.y = sy * inv; o.z = sz * inv; o.w = sw * inv;
    *(float4*)(aggx + (size_t)w * 256 + ch) = o;
}

// ---------------- fused compact->ts aggregation: 4 segments in lockstep -------------
__global__ __launch_bounds__(256) void agg_ts(const float* __restrict__ attnT,
                                              const float* __restrict__ attnC,
                                              const unsigned short* __restrict__ hscbf,
                                              const int* __restrict__ rowptr,
                                              const int* __restrict__ ssrc,
                                              const float* __restrict__ bconv_l,
                                              float* __restrict__ xout)
{
    int d = blockIdx.x * 4 + (threadIdx.x >> 6);   // grid 12500
    int lane = threadIdx.x & 63;
    int h = lane >> 4;
    int ch = (h << 6) | ((lane & 15) << 2);
    const int co4[4]   = {0, 1000, 21000, 26000};
    const int tb4[4]   = {1000, 71000, 126000, 184000};
    const int doff4[4] = {16, 20, 24, 28};
    const int bo4[4]   = {256, 768, 1280, 1792};

    int r0q[4], nq[4]; float edq[4];
    int mx = 0;
#pragma unroll
    for (int q = 0; q < 4; q++) {
        int a = rowptr[tb4[q] + d], b = rowptr[tb4[q] + d + 1];
        r0q[q] = a; nq[q] = b - a;
        mx = max(mx, b - a);
        edq[q] = attnT[(size_t)d * 32 + doff4[q] + h];
    }
    float den[4] = {0.f, 0.f, 0.f, 0.f};
    float sx[4] = {0.f, 0.f, 0.f, 0.f}, sy[4] = {0.f, 0.f, 0.f, 0.f};
    float sz[4] = {0.f, 0.f, 0.f, 0.f}, sw[4] = {0.f, 0.f, 0.f, 0.f};
    for (int i = 0; i < mx; i++) {
#pragma unroll
        for (int q = 0; q < 4; q++) {
            if (i < nq[q]) {
                int s = ssrc[r0q[q] + i];
                float es = attnC[(size_t)(co4[q] + s) * 8 + h];
                float ex = __expf(lrelu(es + edq[q]));
                den[q] += ex;
                ushort4 hv = *(const ushort4*)(hscbf + (size_t)(co4[q] + s) * 256 + ch);
                sx[q] += ex * bf2f(hv.x); sy[q] += ex * bf2f(hv.y);
                sz[q] += ex * bf2f(hv.z); sw[q] += ex * bf2f(hv.w);
            }
        }
    }
    float ax = 0.f, ay = 0.f, az = 0.f, aw = 0.f;
#pragma unroll
    for (int q = 0; q < 4; q++) {
        const float* b = bconv_l + bo4[q] + ch;
        float inv = 1.f / (den[q] + 1e-16f);
        ax += b[0] + sx[q] * inv; ay += b[1] + sy[q] * inv;
        az += b[2] + sz[q] * inv; aw += b[3] + sw[q] * inv;
    }
    float4 o;
    o.x = fmaxf(ax, 0.f); o.y = fmaxf(ay, 0.f);
    o.z = fmaxf(az, 0.f); o.w = fmaxf(aw, 0.f);
    *(float4*)(xout + (size_t)d * 256 + ch) = o;
}

// ---------------- pooling + head ----------------
__global__ __launch_bounds__(256) void colsum_ts(const float* __restrict__ x,
                                                 float* __restrict__ gsum)
{
    int c = threadIdx.x;
    float s = 0.f;
    for (int r = blockIdx.x; r < 50000; r += gridDim.x) s += x[(size_t)r * 256 + c];
    atomAddF(gsum + c, s);
}

__global__ __launch_bounds__(128) void head_k(const float* __restrict__ gsum,
                                              const float* __restrict__ Wc1,
                                              const float* __restrict__ bc1,
                                              const float* __restrict__ Wc2,
                                              const float* __restrict__ bc2,
                                              float* __restrict__ out)
{
    __shared__ float g[256];
    __shared__ float red[128];
    int t = threadIdx.x;
    g[t] = gsum[t] * (1.f / 50000.f);
    g[t + 128] = gsum[t + 128] * (1.f / 50000.f);
    __syncthreads();
    float acc = bc1[t];
    for (int k = 0; k < 256; k++) acc += g[k] * Wc1[k * 128 + t];
    red[t] = fmaxf(acc, 0.f) * Wc2[t];
    __syncthreads();
    for (int sft = 64; sft > 0; sft >>= 1) {
        if (t < sft) red[t] += red[t + sft];
        __syncthreads();
    }
    if (t == 0) out[0] = red[0] + bc2[0];
}

extern "C" void kernel_launch(void* const* d_in, const int* in_sizes, int n_in,
                              void* d_out, int out_size, void* d_ws, size_t ws_size,
                              hipStream_t stream)
{
    const float* ts_x   = (const float*)d_in[0];
    const float* emb[4] = {(const float*)d_in[1], (const float*)d_in[2],
                           (const float*)d_in[3], (const float*)d_in[4]};
    const float* Wp_ts  = (const float*)d_in[5];
    const float* bp_ts  = (const float*)d_in[6];
    const float* Wp_c   = (const float*)d_in[7];
    const float* bp_c   = (const float*)d_in[8];
    const float* Wsrc   = (const float*)d_in[9];
    const float* Wdst   = (const float*)d_in[10];
    const float* asrc   = (const float*)d_in[11];
    const float* adst   = (const float*)d_in[12];
    const float* bconv  = (const float*)d_in[13];
    const float* Wc1    = (const float*)d_in[14];
    const float* bc1    = (const float*)d_in[15];
    const float* Wc2    = (const float*)d_in[16];
    const float* bc2    = (const float*)d_in[17];
    EI8 ei;
    for (int t = 0; t < 8; t++) ei.p[t] = (const int*)d_in[18 + t];

    // workspace layout (float units)
    float* x0    = (float*)d_ws;           // 21,504,000
    float* x1    = x0    + 21504000;       // 21,504,000 (ts region doubles as aggx in L1)
    float* attnT = x1    + 21504000;       // 1,600,000
    float* attnC = attnT + 1600000;        // 272,000
    float* weff  = attnC + 272000;         // 81,920
    float* gsum  = weff  + 81920;          // 256
    int* rowptr  = (int*)(gsum + 256);     // 234,004
    int* bsum    = rowptr + 234004;        // 256
    int* ssrc    = bsum + 256;             // 800,000
    unsigned short* xtsbf = (unsigned short*)(ssrc + 800000);   // 12,800,000 us
    unsigned short* hscbf = xtsbf + 12800000;                   //  8,704,000 us
    unsigned short* btp   = hscbf + 8704000;                    //  1,867,776 us
    int* cursor  = (int*)hscbf;            // alias: CSR build finishes before hscbf used
    float* aggx  = x1;                     // alias ts region of x1

    unsigned short* bt_ts_h = btp;
    unsigned short* bt_ts_l = bt_ts_h + 16384;
    unsigned short* bt_c_h[4], *bt_c_l[4];
    {
        unsigned short* p = bt_ts_l + 16384;
        for (int q = 0; q < 4; q++) { bt_c_h[q] = p; p += 32768; bt_c_l[q] = p; p += 32768; }
    }
    unsigned short* bt_w = bt_ts_l + 16384 + 8 * 32768;
    auto wpan_h = [&](int l, int t) { return bt_w + (size_t)((l == 0 ? t : 8 + t / 2) * 2) * 65536; };
    auto wpan_l = [&](int l, int t) { return wpan_h(l, t) + 65536; };

    // ---- CSR build ----
    hipMemsetAsync(cursor, 0, NDST * sizeof(int), stream);
    count_k<<<3125, 256, 0, stream>>>(ei, cursor);
    scanA<<<229, 256, 0, stream>>>(cursor, rowptr, bsum);
    scanB<<<1, 256, 0, stream>>>(bsum, 229);
    scanC<<<229, 256, 0, stream>>>(rowptr, bsum, cursor);
    place_k<<<3125, 256, 0, stream>>>(ei, cursor, ssrc);

    // ---- weight pre-split ----
    {
        BTBatch b = {};
        int zi = 0;
        b.j[zi++] = {Wp_ts, bt_ts_h, bt_ts_l, 64, 6};
        for (int q = 0; q < 4; q++)
            b.j[zi++] = {Wp_c + q * 32768, bt_c_h[q], bt_c_l[q], 128, 7};
        for (int t = 0; t < 8; t++)
            b.j[zi++] = {Wsrc + (size_t)(0 * 8 + t) * 65536, wpan_h(0, t), wpan_l(0, t), 256, 8};
        for (int t = 1; t < 8; t += 2)
            b.j[zi++] = {Wsrc + (size_t)(1 * 8 + t) * 65536, wpan_h(1, t), wpan_l(1, t), 256, 8};
        makeBT<<<dim3(256, 1, 17), 256, 0, stream>>>(b);
    }

    fill_weff<<<320, 256, 0, stream>>>(Wsrc, Wdst, asrc, adst, weff);

    static const int Nd4[4]    = {1000, 20000, 5000, 8000};
    static const int co4[4]    = {0, 1000, 21000, 26000};
    static const int dbase4[4] = {50000, 51000, 71000, 76000};
    static const int tsrc[4]   = {1, 3, 5, 7};
    static const int tdst[4]   = {0, 2, 4, 6};

    // ---- input projections (ts job also writes bf16 shadow for aggx gather) ----
    {
        MBatch b = {};
        b.j[0] = {ts_x, bt_ts_h, bt_ts_l, x0, xtsbf, bp_ts, 50000, 64, 0};
        for (int q = 0; q < 4; q++)
            b.j[1 + q] = {emb[q], bt_c_h[q], bt_c_l[q], x0 + (size_t)dbase4[q] * 256,
                          nullptr, bp_c + q * 256, Nd4[q], 128, 0};
        gemm_mfma<<<dim3(391, 2, 5), 256, 0, stream>>>(b);
    }

    // ---- layer 1 ----
    attnproj<<<329, 256, 0, stream>>>(x0, weff, attnT, attnC);
    aggx_k<<<8500, 256, 0, stream>>>(attnT, attnC, xtsbf, rowptr, ssrc, aggx);
    {
        MBatch b = {};
        for (int q = 0; q < 4; q++)
            b.j[q] = {x0 + (size_t)dbase4[q] * 256, wpan_h(0, tsrc[q]), wpan_l(0, tsrc[q]),
                      nullptr, hscbf + (size_t)co4[q] * 256, nullptr, Nd4[q], 256, 0};
        for (int q = 0; q < 4; q++)
            b.j[4 + q] = {aggx + (size_t)co4[q] * 256, wpan_h(0, tdst[q]), wpan_l(0, tdst[q]),
                          x1 + (size_t)dbase4[q] * 256, nullptr, bconv + tdst[q] * 256, Nd4[q], 256, 1};
        gemm_mfma<<<dim3(157, 2, 8), 256, 0, stream>>>(b);
    }
    agg_ts<<<12500, 256, 0, stream>>>(attnT, attnC, hscbf, rowptr, ssrc, bconv, x1);

    // ---- layer 2 (ts outputs only) ----
    attnproj<<<329, 256, 0, stream>>>(x1, weff + 40960, attnT, attnC);
    {
        MBatch b = {};
        for (int q = 0; q < 4; q++)
            b.j[q] = {x1 + (size_t)dbase4[q] * 256, wpan_h(1, tsrc[q]), wpan_l(1, tsrc[q]),
                      nullptr, hscbf + (size_t)co4[q] * 256, nullptr, Nd4[q], 256, 0};
        gemm_mfma<<<dim3(157, 2, 4), 256, 0, stream>>>(b);
    }
    agg_ts<<<12500, 256, 0, stream>>>(attnT, attnC, hscbf, rowptr, ssrc, bconv + 2048, x0);

    // ---- pooling + head ----
    hipMemsetAsync(gsum, 0, 256 * sizeof(float), stream);
    colsum_ts<<<256, 256, 0, stream>>>(x0, gsum);
    head_k<<<1, 128, 0, stream>>>(gsum, Wc1, bc1, Wc2, bc2, (float*)d_out);
}